// Round 6
// baseline (434.814 us; speedup 1.0000x reference)
//
#include <hip/hip_runtime.h>

typedef unsigned short u16;
typedef __attribute__((ext_vector_type(8))) short short8;
typedef __attribute__((ext_vector_type(4))) float f32x4;

#define CB 2
#define CS 2048
#define CD 1024
#define CH 16
#define CDH 64
#define CDFF 4096
#define NQB (CS / 64)   // 32 q-blocks of 64

__device__ __forceinline__ u16 f2bf(float f){
  union { float f; unsigned u; } x; x.f = f;
  unsigned r = (x.u + 0x7fffu + ((x.u >> 16) & 1u)) >> 16;
  return (u16)r;
}

// cheap round for positive values (P matrix): round-half-up, 2 VALU ops
__device__ __forceinline__ u16 f2bf_pos(float f){
  union { float f; unsigned u; } x; x.f = f;
  return (u16)((x.u + 0x8000u) >> 16);
}

__device__ __forceinline__ void gload_lds16(const void* g, void* l){
  __builtin_amdgcn_global_load_lds(
    (const __attribute__((address_space(1))) void*)(unsigned long long)g,
    (__attribute__((address_space(3))) void*)(unsigned long long)l,
    16, 0, 0);
}

// ---------------- all 6 weight transposes ([K][N] f32 -> [N][K] bf16) in ONE launch
// blocks 0..4095: Wq,Wk,Wv,Wo (1024 tiles each); 4096..8191: w1; 8192..12287: w2
struct TPAll { const float* s[6]; u16* d[6]; };

__global__ __launch_bounds__(256)
void transpose_all(TPAll p)
{
  __shared__ float t[32][33];
  const int g = blockIdx.x >> 12;
  const int id = blockIdx.x & 4095;
  const float* __restrict__ in;
  u16* __restrict__ out;
  int K, N, n0, k0;
  if (g == 0){
    const int w = id >> 10, tile = id & 1023;
    in = p.s[w]; out = p.d[w]; K = 1024; N = 1024;
    n0 = (tile & 31) * 32; k0 = (tile >> 5) * 32;
  } else if (g == 1){
    in = p.s[4]; out = p.d[4]; K = 1024; N = 4096;
    n0 = (id & 127) * 32; k0 = (id >> 7) * 32;
  } else {
    in = p.s[5]; out = p.d[5]; K = 4096; N = 1024;
    n0 = (id & 31) * 32; k0 = (id >> 5) * 32;
  }
  const int c = threadIdx.x & 31, r4 = threadIdx.x >> 5;
  #pragma unroll
  for (int i = 0; i < 4; i++){
    int r = r4 + i * 8;
    t[r][c] = in[(size_t)(k0 + r) * N + n0 + c];
  }
  __syncthreads();
  #pragma unroll
  for (int i = 0; i < 4; i++){
    int r = r4 + i * 8;
    out[(size_t)(n0 + r) * K + k0 + c] = f2bf(t[c][r]);
  }
}

// ---------------- LayerNorm: fp32 row [1024] -> bf16 row, one block per row
// MODE 1: also write aux = v (fp32 copy of input row)
// MODE 2: also write aux = v + bias (fp32, may alias xin — per-thread in-place)
template<int MODE>
__global__ __launch_bounds__(256)
void ln_bf16(const float* __restrict__ xin, const float* __restrict__ g,
             const float* __restrict__ be, u16* __restrict__ outp,
             float4* __restrict__ aux, const float* __restrict__ bias)
{
  const int row = blockIdx.x, tid = threadIdx.x;
  const int lane = tid & 63, wave = tid >> 6;
  const float4 v = ((const float4*)(xin + (size_t)row * CD))[tid];
  float s  = v.x + v.y + v.z + v.w;
  float s2 = v.x*v.x + v.y*v.y + v.z*v.z + v.w*v.w;
  #pragma unroll
  for (int m = 1; m < 64; m <<= 1){ s += __shfl_xor(s, m); s2 += __shfl_xor(s2, m); }
  __shared__ float red[8];
  if (lane == 0){ red[wave] = s; red[4 + wave] = s2; }

  if (MODE == 1){
    aux[(size_t)row * 256 + tid] = v;
  } else if (MODE == 2){
    const float4 b4 = ((const float4*)bias)[tid];
    float4 w = v;
    w.x += b4.x; w.y += b4.y; w.z += b4.z; w.w += b4.w;
    aux[(size_t)row * 256 + tid] = w;
  }

  __syncthreads();
  s  = red[0] + red[1] + red[2] + red[3];
  s2 = red[4] + red[5] + red[6] + red[7];
  const float mu = s * (1.0f / CD);
  const float var = s2 * (1.0f / CD) - mu * mu;
  const float rs = rsqrtf(var + 1e-5f);
  const float4 gv = ((const float4*)g)[tid];
  const float4 bv = ((const float4*)be)[tid];
  ushort4 o;
  o.x = f2bf((v.x - mu) * rs * gv.x + bv.x);
  o.y = f2bf((v.y - mu) * rs * gv.y + bv.y);
  o.z = f2bf((v.z - mu) * rs * gv.z + bv.z);
  o.w = f2bf((v.w - mu) * rs * gv.w + bv.w);
  ((ushort4*)outp)[(size_t)row * (CD / 4) + tid] = o;
}

// ---------------- GEMM: C[M,N] = A[M,K] (bf16) * Bt[N,K]^T (bf16)
// 1-D grid, XCD-banded swizzle: tile = (flat%8)*(G/8) + flat/8, decoded
// n-fastest, z-outermost -> each XCD owns (one z, m-band, all n): small L2 set.
// EPI 0 (QKV): store bf16; Q cols (<1024) pre-scaled 0.125; n0>=vsplit -> V^T.
// EPI 1: +bias, relu, store bf16
// EPI 3: unsafeAtomicAdd into f32 output (split-K partials)
template<int EPI>
__global__ __launch_bounds__(256)
void gemm_bt(const u16* __restrict__ A, const u16* __restrict__ Bt,
             void* __restrict__ Cout, const float* __restrict__ bias,
             int M, int N, int K,
             int ldc, int vsplit, u16* __restrict__ vtout)
{
  __shared__ __align__(16) u16 lA[128 * 64];
  __shared__ __align__(16) u16 lB[128 * 64];
  const int tid = threadIdx.x;
  const int wave = tid >> 6, lane = tid & 63;

  // XCD-banded tile decode
  const int G = gridDim.x;
  const int flat = blockIdx.x;
  const int t = (flat & 7) * (G >> 3) + (flat >> 3);
  const int NN = N >> 7, NM = M >> 7;
  const int n_i = t % NN;
  const int rem = t / NN;
  const int m_i = rem % NM;
  const int z   = rem / NM;
  const int NZ  = G / (NN * NM);

  const int m0 = m_i * 128, n0 = n_i * 128;
  const int wm = (wave >> 1) * 64, wn = (wave & 1) * 64;
  const int lq = lane >> 4, lr = lane & 15;

  f32x4 acc[4][4] = {};

  const u16* Ab = A + (size_t)m0 * K;
  const u16* Bb = Bt + (size_t)n0 * K;
  const int srow = lane >> 3;          // 0..7 within a 1KB chunk
  const int scol = (lane & 7) * 8;

  const int kpb = K / NZ;
  const int kbeg = z * kpb, kend = kbeg + kpb;

  for (int k0 = kbeg; k0 < kend; k0 += 64){
    __syncthreads();
    #pragma unroll
    for (int i = 0; i < 4; i++){
      const int c = i * 4 + wave;          // chunk 0..15 (1 KB each)
      const int row = c * 8 + srow;
      gload_lds16(Ab + (size_t)row * K + k0 + scol, &lA[c * 512]);
      gload_lds16(Bb + (size_t)row * K + k0 + scol, &lB[c * 512]);
    }
    __syncthreads();
    #pragma unroll
    for (int kk = 0; kk < 64; kk += 32){
      short8 aF[4], bF[4];
      #pragma unroll
      for (int i = 0; i < 4; i++) aF[i] = *(const short8*)&lA[(wm + i * 16 + lr) * 64 + kk + lq * 8];
      #pragma unroll
      for (int j = 0; j < 4; j++) bF[j] = *(const short8*)&lB[(wn + j * 16 + lr) * 64 + kk + lq * 8];
      #pragma unroll
      for (int i = 0; i < 4; i++)
        #pragma unroll
        for (int j = 0; j < 4; j++)
          acc[i][j] = __builtin_amdgcn_mfma_f32_16x16x32_bf16(aF[i], bF[j], acc[i][j], 0, 0, 0);
    }
  }

  if (EPI == 0 && n0 >= vsplit){
    // V block: store transposed into vt[(b*16+h)*64+d][s], s = 4 consecutive rows
    #pragma unroll
    for (int i = 0; i < 4; i++){
      const int row0 = m0 + wm + i * 16 + lq * 4;
      const int bb = row0 >> 11, s = row0 & 2047;
      #pragma unroll
      for (int j = 0; j < 4; j++){
        const int col = n0 - vsplit + wn + j * 16 + lr;  // 0..1023 = h*64+d
        ushort4 o;
        o.x = f2bf(acc[i][j][0]); o.y = f2bf(acc[i][j][1]);
        o.z = f2bf(acc[i][j][2]); o.w = f2bf(acc[i][j][3]);
        *(ushort4*)&vtout[((size_t)(bb * 1024 + col)) * CS + s] = o;
      }
    }
    return;
  }

  // Q pre-scale for attention (EPI 0 / QKV only): cols < 1024 are Q
  const float osc = (EPI == 0 && n0 < 1024) ? 0.125f : 1.0f;

  #pragma unroll
  for (int i = 0; i < 4; i++){
    const int row = m0 + wm + i * 16 + lq * 4;
    #pragma unroll
    for (int j = 0; j < 4; j++){
      const int col = n0 + wn + j * 16 + lr;
      #pragma unroll
      for (int r = 0; r < 4; r++){
        float v = acc[i][j][r];
        const size_t off = (size_t)(row + r) * ldc + col;
        if (EPI == 0){
          ((u16*)Cout)[off] = f2bf(v * osc);
        } else if (EPI == 1){
          v += bias[col]; v = v > 0.0f ? v : 0.0f;
          ((u16*)Cout)[off] = f2bf(v);
        } else {
          unsafeAtomicAdd(&((float*)Cout)[off], v);
        }
      }
    }
  }
}

// ---------------- causal flash attention, balanced q-block pairs, 64-key tiles
// Grid: x = bh (32, mult of 8 -> XCD L2 locality for K/V), y = pair.
// No running max (scores statically bounded); Q pre-scaled by 0.125.
// qk: bf16 [B*S][2048] (Q | K), vt: bf16 [B*H*DH][S], out: bf16 [B*S][1024]
__global__ __launch_bounds__(256)
void attn_kernel(const u16* __restrict__ qk, const u16* __restrict__ vt,
                 u16* __restrict__ outp)
{
  __shared__ __align__(16) u16 lK[64 * 64];     // [key][d]   8 KB
  __shared__ __align__(16) u16 lVt[64 * 64];    // [d][key]   8 KB
  __shared__ __align__(16) u16 lP[4][16 * 72];  // per-wave P, padded  9 KB
  const int tid = threadIdx.x, wave = tid >> 6, lane = tid & 63;
  const int lq = lane >> 4, lr = lane & 15;
  const int bh = blockIdx.x, b = bh >> 4, h = bh & 15;
  const int RS = 2048;
  const int srow = lane >> 3, scol = (lane & 7) * 8;

  const size_t kbase = (size_t)(b * CS) * RS + 1024 + h * CDH;
  const size_t vbase = (size_t)(bh * CDH) * CS;
  u16* lPw = lP[wave];

  #pragma unroll 1
  for (int part = 0; part < 2; part++){
    const int iq = part ? (NQB - 1 - blockIdx.y) : blockIdx.y;
    const int q0 = iq * 64;
    const int ktmax = iq + 1;

    // Q fragments (A-layout): m = lr, k = lq*8 + j (+32); already * 0.125
    const int qrow = b * CS + q0 + wave * 16 + lr;
    const u16* qp = qk + (size_t)qrow * RS + h * CDH;
    const short8 qf0 = *(const short8*)(qp + lq * 8);
    const short8 qf1 = *(const short8*)(qp + 32 + lq * 8);

    f32x4 o[4] = {};
    float lsum[4] = {0.0f, 0.0f, 0.0f, 0.0f};

    for (int kt = 0; kt < ktmax; ++kt){
      __syncthreads();
      #pragma unroll
      for (int cc = 0; cc < 2; cc++){
        const int c = wave * 2 + cc;             // chunk 0..7, 8 rows each
        gload_lds16(qk + kbase + (size_t)(kt * 64 + c * 8 + srow) * RS + scol, &lK[c * 512]);
        gload_lds16(vt + vbase + (size_t)(c * 8 + srow) * CS + kt * 64 + scol, &lVt[c * 512]);
      }
      __syncthreads();

      // S = Q K^T : 16 q-rows x 64 keys (pre-scaled)
      f32x4 s[4] = {};
      #pragma unroll
      for (int nb = 0; nb < 4; nb++){
        const short8 bk0 = *(const short8*)&lK[(nb * 16 + lr) * 64 + lq * 8];
        const short8 bk1 = *(const short8*)&lK[(nb * 16 + lr) * 64 + 32 + lq * 8];
        s[nb] = __builtin_amdgcn_mfma_f32_16x16x32_bf16(qf0, bk0, s[nb], 0, 0, 0);
        s[nb] = __builtin_amdgcn_mfma_f32_16x16x32_bf16(qf1, bk1, s[nb], 0, 0, 0);
      }

      const bool diag = (kt + 1) == ktmax;       // only diagonal tile needs mask
      const int qg = q0 + wave * 16 + lq * 4;
      #pragma unroll
      for (int r = 0; r < 4; r++){
        float e0 = __expf(s[0][r]);
        float e1 = __expf(s[1][r]);
        float e2 = __expf(s[2][r]);
        float e3 = __expf(s[3][r]);
        if (diag){
          const int q = qg + r, kb = kt * 64 + lr;
          e0 = (kb      <= q) ? e0 : 0.0f;
          e1 = (kb + 16 <= q) ? e1 : 0.0f;
          e2 = (kb + 32 <= q) ? e2 : 0.0f;
          e3 = (kb + 48 <= q) ? e3 : 0.0f;
        }
        lsum[r] += (e0 + e1) + (e2 + e3);
        const int prow = (lq * 4 + r) * 72;
        lPw[prow + lr]      = f2bf_pos(e0);
        lPw[prow + 16 + lr] = f2bf_pos(e1);
        lPw[prow + 32 + lr] = f2bf_pos(e2);
        lPw[prow + 48 + lr] = f2bf_pos(e3);
      }

      // P: C-layout -> A-layout via per-wave LDS
      asm volatile("s_waitcnt lgkmcnt(0)" ::: "memory");
      const short8 pf0 = *(const short8*)&lPw[lr * 72 + lq * 8];
      const short8 pf1 = *(const short8*)&lPw[lr * 72 + 32 + lq * 8];

      #pragma unroll
      for (int nb = 0; nb < 4; nb++){
        const short8 bv0 = *(const short8*)&lVt[(nb * 16 + lr) * 64 + lq * 8];
        const short8 bv1 = *(const short8*)&lVt[(nb * 16 + lr) * 64 + 32 + lq * 8];
        o[nb] = __builtin_amdgcn_mfma_f32_16x16x32_bf16(pf0, bv0, o[nb], 0, 0, 0);
        o[nb] = __builtin_amdgcn_mfma_f32_16x16x32_bf16(pf1, bv1, o[nb], 0, 0, 0);
      }
    }

    // one reduction tree per part: sum over the 16 key-lanes (lr)
    #pragma unroll
    for (int r = 0; r < 4; r++){
      float l = lsum[r];
      l += __shfl_xor(l, 1);
      l += __shfl_xor(l, 2);
      l += __shfl_xor(l, 4);
      l += __shfl_xor(l, 8);
      const float inv = __builtin_amdgcn_rcpf(l);
      const size_t row = (size_t)(b * CS + q0 + wave * 16 + lq * 4 + r);
      #pragma unroll
      for (int nb = 0; nb < 4; nb++)
        outp[row * CD + h * CDH + nb * 16 + lr] = f2bf(o[nb][r] * inv);
    }
  }
}

extern "C" void kernel_launch(void* const* d_in, const int* in_sizes, int n_in,
                              void* d_out, int out_size, void* d_ws, size_t ws_size,
                              hipStream_t stream)
{
  const float* x   = (const float*)d_in[0];
  const float* Wq  = (const float*)d_in[2];
  const float* Wk  = (const float*)d_in[3];
  const float* Wv  = (const float*)d_in[4];
  const float* Wo  = (const float*)d_in[5];
  const float* w1  = (const float*)d_in[6];
  const float* b1  = (const float*)d_in[7];
  const float* w2  = (const float*)d_in[8];
  const float* b2  = (const float*)d_in[9];
  const float* g1  = (const float*)d_in[10];
  const float* be1 = (const float*)d_in[11];
  const float* g2  = (const float*)d_in[12];
  const float* be2 = (const float*)d_in[13];
  float* out = (float*)d_out;

  char* ws = (char*)d_ws;
  const size_t MB = 1u << 20;
  u16* yln    = (u16*)(ws);              // [4096][1024] bf16 (also hn)       8 MB
  u16* qk     = (u16*)(ws + 8  * MB);    // [4096][2048] bf16 (Q|K)          16 MB
  u16* vt     = (u16*)(ws + 24 * MB);    // [B*H*64][2048] bf16 (V^T)         8 MB
  u16* attn   = (u16*)(ws + 32 * MB);    // [4096][1024] bf16                 8 MB
  u16* mid    = (u16*)(ws + 40 * MB);    // [4096][4096] bf16                32 MB
  u16* Wqkv_t = (u16*)(ws + 72 * MB);    // [3072][1024] bf16                 6 MB
  u16* Wo_t   = (u16*)(ws + 78 * MB);    // [1024][1024] bf16                 2 MB
  u16* w1_t   = (u16*)(ws + 80 * MB);    // [4096][1024] bf16                 8 MB
  u16* w2_t   = (u16*)(ws + 88 * MB);    // [1024][4096] bf16                 8 MB

  const int M = CB * CS;  // 4096
  const int BIG = 1 << 30;

  // weight prep: all 6 transposes in one launch
  TPAll pa;
  pa.s[0] = Wq; pa.s[1] = Wk; pa.s[2] = Wv; pa.s[3] = Wo; pa.s[4] = w1; pa.s[5] = w2;
  pa.d[0] = Wqkv_t;
  pa.d[1] = Wqkv_t + (size_t)CD * CD;
  pa.d[2] = Wqkv_t + (size_t)2 * CD * CD;
  pa.d[3] = Wo_t;
  pa.d[4] = w1_t;
  pa.d[5] = w2_t;
  transpose_all<<<3 * 4096, 256, 0, stream>>>(pa);

  // LN1: x -> yln (bf16); also out = x (residual init for Wo atomics)
  ln_bf16<1><<<M, 256, 0, stream>>>(x, g1, be1, yln, (float4*)out, nullptr);
  // QKV: Q,K -> qk (ldc=2048, Q pre-scaled 0.125); V -> vt (transposed)
  gemm_bt<0><<<24 * 32, 256, 0, stream>>>(yln, Wqkv_t, qk, nullptr, M, 3 * CD, CD, 2048, 2048, vt);
  // attention (grid: x=bh for XCD L2 locality, y=pair)
  attn_kernel<<<dim3(CB * CH, NQB / 2), 256, 0, stream>>>(qk, vt, attn);
  // h = out += attn @ Wo  (split-K=2, atomic f32)
  gemm_bt<3><<<8 * 32 * 2, 256, 0, stream>>>(attn, Wo_t, out, nullptr, M, CD, CD, CD, BIG, nullptr);
  // LN2: h -> hn (bf16); also out = h + b2 in-place (residual+bias init for FFN2)
  ln_bf16<2><<<M, 256, 0, stream>>>(out, g2, be2, yln, (float4*)out, b2);
  // mid = relu(hn @ w1 + b1)
  gemm_bt<1><<<32 * 32, 256, 0, stream>>>(yln, w1_t, mid, b1, M, CDFF, CD, CDFF, BIG, nullptr);
  // out += mid @ w2  (split-K=4, atomic f32, 1024 blocks = 4/CU)
  gemm_bt<3><<<8 * 32 * 4, 256, 0, stream>>>(mid, w2_t, out, nullptr, M, CD, CDFF, CD, BIG, nullptr);
}

// Round 7
// 405.274 us; speedup vs baseline: 1.0729x; 1.0729x over previous
//
#include <hip/hip_runtime.h>

typedef unsigned short u16;
typedef __attribute__((ext_vector_type(8))) short short8;
typedef __attribute__((ext_vector_type(4))) float f32x4;

#define CB 2
#define CS 2048
#define CD 1024
#define CH 16
#define CDH 64
#define CDFF 4096
#define NQB (CS / 64)   // 32 q-blocks of 64

__device__ __forceinline__ u16 f2bf(float f){
  union { float f; unsigned u; } x; x.f = f;
  unsigned r = (x.u + 0x7fffu + ((x.u >> 16) & 1u)) >> 16;
  return (u16)r;
}

// cheap round for positive values (P matrix): round-half-up, 2 VALU ops
__device__ __forceinline__ u16 f2bf_pos(float f){
  union { float f; unsigned u; } x; x.f = f;
  return (u16)((x.u + 0x8000u) >> 16);
}

__device__ __forceinline__ void gload_lds16(const void* g, void* l){
  __builtin_amdgcn_global_load_lds(
    (const __attribute__((address_space(1))) void*)(unsigned long long)g,
    (__attribute__((address_space(3))) void*)(unsigned long long)l,
    16, 0, 0);
}

// ---------------- all 6 weight transposes ([K][N] f32 -> [N][K] bf16) in ONE launch
struct TPAll { const float* s[6]; u16* d[6]; };

__global__ __launch_bounds__(256)
void transpose_all(TPAll p)
{
  __shared__ float t[32][33];
  const int g = blockIdx.x >> 12;
  const int id = blockIdx.x & 4095;
  const float* __restrict__ in;
  u16* __restrict__ out;
  int K, N, n0, k0;
  if (g == 0){
    const int w = id >> 10, tile = id & 1023;
    in = p.s[w]; out = p.d[w]; K = 1024; N = 1024;
    n0 = (tile & 31) * 32; k0 = (tile >> 5) * 32;
  } else if (g == 1){
    in = p.s[4]; out = p.d[4]; K = 1024; N = 4096;
    n0 = (id & 127) * 32; k0 = (id >> 7) * 32;
  } else {
    in = p.s[5]; out = p.d[5]; K = 4096; N = 1024;
    n0 = (id & 31) * 32; k0 = (id >> 5) * 32;
  }
  const int c = threadIdx.x & 31, r4 = threadIdx.x >> 5;
  #pragma unroll
  for (int i = 0; i < 4; i++){
    int r = r4 + i * 8;
    t[r][c] = in[(size_t)(k0 + r) * N + n0 + c];
  }
  __syncthreads();
  #pragma unroll
  for (int i = 0; i < 4; i++){
    int r = r4 + i * 8;
    out[(size_t)(n0 + r) * K + k0 + c] = f2bf(t[c][r]);
  }
}

// ---------------- LayerNorm: fp32 row [1024] -> bf16 row, one block per row
// MODE 0: LN only.  MODE 2: also write aux = v + bias (fp32, may alias xin)
template<int MODE>
__global__ __launch_bounds__(256)
void ln_bf16(const float* __restrict__ xin, const float* __restrict__ g,
             const float* __restrict__ be, u16* __restrict__ outp,
             float4* __restrict__ aux, const float* __restrict__ bias)
{
  const int row = blockIdx.x, tid = threadIdx.x;
  const int lane = tid & 63, wave = tid >> 6;
  const float4 v = ((const float4*)(xin + (size_t)row * CD))[tid];
  float s  = v.x + v.y + v.z + v.w;
  float s2 = v.x*v.x + v.y*v.y + v.z*v.z + v.w*v.w;
  #pragma unroll
  for (int m = 1; m < 64; m <<= 1){ s += __shfl_xor(s, m); s2 += __shfl_xor(s2, m); }
  __shared__ float red[8];
  if (lane == 0){ red[wave] = s; red[4 + wave] = s2; }

  if (MODE == 2){
    const float4 b4 = ((const float4*)bias)[tid];
    float4 w = v;
    w.x += b4.x; w.y += b4.y; w.z += b4.z; w.w += b4.w;
    aux[(size_t)row * 256 + tid] = w;
  }

  __syncthreads();
  s  = red[0] + red[1] + red[2] + red[3];
  s2 = red[4] + red[5] + red[6] + red[7];
  const float mu = s * (1.0f / CD);
  const float var = s2 * (1.0f / CD) - mu * mu;
  const float rs = rsqrtf(var + 1e-5f);
  const float4 gv = ((const float4*)g)[tid];
  const float4 bv = ((const float4*)be)[tid];
  ushort4 o;
  o.x = f2bf((v.x - mu) * rs * gv.x + bv.x);
  o.y = f2bf((v.y - mu) * rs * gv.y + bv.y);
  o.z = f2bf((v.z - mu) * rs * gv.z + bv.z);
  o.w = f2bf((v.w - mu) * rs * gv.w + bv.w);
  ((ushort4*)outp)[(size_t)row * (CD / 4) + tid] = o;
}

// ---------------- GEMM 128x128: C[M,N] = A[M,K] (bf16) * Bt[N,K]^T (bf16)
// 1-D grid, XCD-banded swizzle. EPI 0 (QKV): store bf16, Q pre-scaled 0.125,
// n0>=vsplit -> V^T.  EPI 1: +bias, relu, store bf16.
template<int EPI>
__global__ __launch_bounds__(256)
void gemm_bt(const u16* __restrict__ A, const u16* __restrict__ Bt,
             void* __restrict__ Cout, const float* __restrict__ bias,
             int M, int N, int K,
             int ldc, int vsplit, u16* __restrict__ vtout)
{
  __shared__ __align__(16) u16 lA[128 * 64];
  __shared__ __align__(16) u16 lB[128 * 64];
  const int tid = threadIdx.x;
  const int wave = tid >> 6, lane = tid & 63;

  // XCD-banded tile decode (n-fastest)
  const int G = gridDim.x;
  const int flat = blockIdx.x;
  const int t = (flat & 7) * (G >> 3) + (flat >> 3);
  const int NN = N >> 7;
  const int n_i = t % NN;
  const int m_i = t / NN;

  const int m0 = m_i * 128, n0 = n_i * 128;
  const int wm = (wave >> 1) * 64, wn = (wave & 1) * 64;
  const int lq = lane >> 4, lr = lane & 15;

  f32x4 acc[4][4] = {};

  const u16* Ab = A + (size_t)m0 * K;
  const u16* Bb = Bt + (size_t)n0 * K;
  const int srow = lane >> 3;          // 0..7 within a 1KB chunk
  const int scol = (lane & 7) * 8;

  for (int k0 = 0; k0 < K; k0 += 64){
    __syncthreads();
    #pragma unroll
    for (int i = 0; i < 4; i++){
      const int c = i * 4 + wave;          // chunk 0..15 (1 KB each)
      const int row = c * 8 + srow;
      gload_lds16(Ab + (size_t)row * K + k0 + scol, &lA[c * 512]);
      gload_lds16(Bb + (size_t)row * K + k0 + scol, &lB[c * 512]);
    }
    __syncthreads();
    #pragma unroll
    for (int kk = 0; kk < 64; kk += 32){
      short8 aF[4], bF[4];
      #pragma unroll
      for (int i = 0; i < 4; i++) aF[i] = *(const short8*)&lA[(wm + i * 16 + lr) * 64 + kk + lq * 8];
      #pragma unroll
      for (int j = 0; j < 4; j++) bF[j] = *(const short8*)&lB[(wn + j * 16 + lr) * 64 + kk + lq * 8];
      #pragma unroll
      for (int i = 0; i < 4; i++)
        #pragma unroll
        for (int j = 0; j < 4; j++)
          acc[i][j] = __builtin_amdgcn_mfma_f32_16x16x32_bf16(aF[i], bF[j], acc[i][j], 0, 0, 0);
    }
  }

  if (EPI == 0 && n0 >= vsplit){
    // V block: store transposed into vt[(b*16+h)*64+d][s], s = 4 consecutive rows
    #pragma unroll
    for (int i = 0; i < 4; i++){
      const int row0 = m0 + wm + i * 16 + lq * 4;
      const int bb = row0 >> 11, s = row0 & 2047;
      #pragma unroll
      for (int j = 0; j < 4; j++){
        const int col = n0 - vsplit + wn + j * 16 + lr;  // 0..1023 = h*64+d
        ushort4 o;
        o.x = f2bf(acc[i][j][0]); o.y = f2bf(acc[i][j][1]);
        o.z = f2bf(acc[i][j][2]); o.w = f2bf(acc[i][j][3]);
        *(ushort4*)&vtout[((size_t)(bb * 1024 + col)) * CS + s] = o;
      }
    }
    return;
  }

  // Q pre-scale for attention (EPI 0 / QKV only): cols < 1024 are Q
  const float osc = (EPI == 0 && n0 < 1024) ? 0.125f : 1.0f;

  #pragma unroll
  for (int i = 0; i < 4; i++){
    const int row = m0 + wm + i * 16 + lq * 4;
    #pragma unroll
    for (int j = 0; j < 4; j++){
      const int col = n0 + wn + j * 16 + lr;
      #pragma unroll
      for (int r = 0; r < 4; r++){
        float v = acc[i][j][r];
        const size_t off = (size_t)(row + r) * ldc + col;
        if (EPI == 0){
          ((u16*)Cout)[off] = f2bf(v * osc);
        } else {
          v += bias[col]; v = v > 0.0f ? v : 0.0f;
          ((u16*)Cout)[off] = f2bf(v);
        }
      }
    }
  }
}

// ---------------- GEMM 64x128, no split-K, no atomics:
// Cout[M,N] (f32) = resid[M,N] (f32) + A[M,K] (bf16) * Bt[N,K]^T
// Each 64-row M-tile owns its output rows exclusively; resid may alias Cout.
// Grid = (M/64)*(N/128), XCD-banded, n-fastest.
__global__ __launch_bounds__(256)
void gemm_bt64(const u16* __restrict__ A, const u16* __restrict__ Bt,
               const float* __restrict__ resid, float* __restrict__ Cout,
               int M, int N, int K)
{
  __shared__ __align__(16) u16 lA[64 * 64];    //  8 KB
  __shared__ __align__(16) u16 lB[128 * 64];   // 16 KB
  const int tid = threadIdx.x;
  const int wave = tid >> 6, lane = tid & 63;

  const int G = gridDim.x;
  const int flat = blockIdx.x;
  const int t = (flat & 7) * (G >> 3) + (flat >> 3);
  const int NN = N >> 7;
  const int n_i = t % NN;
  const int m_i = t / NN;
  const int m0 = m_i * 64, n0 = n_i * 128;
  const int lq = lane >> 4, lr = lane & 15;

  f32x4 acc[4][2] = {};

  const u16* Ab = A + (size_t)m0 * K;
  const u16* Bb = Bt + (size_t)n0 * K;
  const int srow = lane >> 3, scol = (lane & 7) * 8;

  for (int k0 = 0; k0 < K; k0 += 64){
    __syncthreads();
    #pragma unroll
    for (int i = 0; i < 6; i++){
      const int c = i * 4 + wave;          // 0..23: chunks 0-7 = A, 8-23 = B
      if (c < 8){
        gload_lds16(Ab + (size_t)(c * 8 + srow) * K + k0 + scol, &lA[c * 512]);
      } else {
        const int cb = c - 8;
        gload_lds16(Bb + (size_t)(cb * 8 + srow) * K + k0 + scol, &lB[cb * 512]);
      }
    }
    __syncthreads();
    #pragma unroll
    for (int kk = 0; kk < 64; kk += 32){
      short8 aF[4], bF[2];
      #pragma unroll
      for (int i = 0; i < 4; i++) aF[i] = *(const short8*)&lA[(i * 16 + lr) * 64 + kk + lq * 8];
      #pragma unroll
      for (int j = 0; j < 2; j++) bF[j] = *(const short8*)&lB[(wave * 32 + j * 16 + lr) * 64 + kk + lq * 8];
      #pragma unroll
      for (int i = 0; i < 4; i++)
        #pragma unroll
        for (int j = 0; j < 2; j++)
          acc[i][j] = __builtin_amdgcn_mfma_f32_16x16x32_bf16(aF[i], bF[j], acc[i][j], 0, 0, 0);
    }
  }

  #pragma unroll
  for (int i = 0; i < 4; i++){
    const int row = m0 + i * 16 + lq * 4;
    #pragma unroll
    for (int j = 0; j < 2; j++){
      const int col = n0 + wave * 32 + j * 16 + lr;
      #pragma unroll
      for (int r = 0; r < 4; r++){
        const size_t off = (size_t)(row + r) * N + col;
        Cout[off] = resid[off] + acc[i][j][r];
      }
    }
  }
}

// ---------------- causal flash attention, balanced q-block pairs, 64-key tiles
// Grid: x = bh (32, mult of 8 -> XCD L2 locality for K/V), y = pair.
// No running max (scores statically bounded); Q pre-scaled by 0.125.
// qk: bf16 [B*S][2048] (Q | K), vt: bf16 [B*H*DH][S], out: bf16 [B*S][1024]
__global__ __launch_bounds__(256)
void attn_kernel(const u16* __restrict__ qk, const u16* __restrict__ vt,
                 u16* __restrict__ outp)
{
  __shared__ __align__(16) u16 lK[64 * 64];     // [key][d]   8 KB
  __shared__ __align__(16) u16 lVt[64 * 64];    // [d][key]   8 KB
  __shared__ __align__(16) u16 lP[4][16 * 72];  // per-wave P, padded  9 KB
  const int tid = threadIdx.x, wave = tid >> 6, lane = tid & 63;
  const int lq = lane >> 4, lr = lane & 15;
  const int bh = blockIdx.x, b = bh >> 4, h = bh & 15;
  const int RS = 2048;
  const int srow = lane >> 3, scol = (lane & 7) * 8;

  const size_t kbase = (size_t)(b * CS) * RS + 1024 + h * CDH;
  const size_t vbase = (size_t)(bh * CDH) * CS;
  u16* lPw = lP[wave];

  #pragma unroll 1
  for (int part = 0; part < 2; part++){
    const int iq = part ? (NQB - 1 - blockIdx.y) : blockIdx.y;
    const int q0 = iq * 64;
    const int ktmax = iq + 1;

    // Q fragments (A-layout): m = lr, k = lq*8 + j (+32); already * 0.125
    const int qrow = b * CS + q0 + wave * 16 + lr;
    const u16* qp = qk + (size_t)qrow * RS + h * CDH;
    const short8 qf0 = *(const short8*)(qp + lq * 8);
    const short8 qf1 = *(const short8*)(qp + 32 + lq * 8);

    f32x4 o[4] = {};
    float lsum[4] = {0.0f, 0.0f, 0.0f, 0.0f};

    for (int kt = 0; kt < ktmax; ++kt){
      __syncthreads();
      #pragma unroll
      for (int cc = 0; cc < 2; cc++){
        const int c = wave * 2 + cc;             // chunk 0..7, 8 rows each
        gload_lds16(qk + kbase + (size_t)(kt * 64 + c * 8 + srow) * RS + scol, &lK[c * 512]);
        gload_lds16(vt + vbase + (size_t)(c * 8 + srow) * CS + kt * 64 + scol, &lVt[c * 512]);
      }
      __syncthreads();

      // S = Q K^T : 16 q-rows x 64 keys (pre-scaled)
      f32x4 s[4] = {};
      #pragma unroll
      for (int nb = 0; nb < 4; nb++){
        const short8 bk0 = *(const short8*)&lK[(nb * 16 + lr) * 64 + lq * 8];
        const short8 bk1 = *(const short8*)&lK[(nb * 16 + lr) * 64 + 32 + lq * 8];
        s[nb] = __builtin_amdgcn_mfma_f32_16x16x32_bf16(qf0, bk0, s[nb], 0, 0, 0);
        s[nb] = __builtin_amdgcn_mfma_f32_16x16x32_bf16(qf1, bk1, s[nb], 0, 0, 0);
      }

      const bool diag = (kt + 1) == ktmax;       // only diagonal tile needs mask
      const int qg = q0 + wave * 16 + lq * 4;
      #pragma unroll
      for (int r = 0; r < 4; r++){
        float e0 = __expf(s[0][r]);
        float e1 = __expf(s[1][r]);
        float e2 = __expf(s[2][r]);
        float e3 = __expf(s[3][r]);
        if (diag){
          const int q = qg + r, kb = kt * 64 + lr;
          e0 = (kb      <= q) ? e0 : 0.0f;
          e1 = (kb + 16 <= q) ? e1 : 0.0f;
          e2 = (kb + 32 <= q) ? e2 : 0.0f;
          e3 = (kb + 48 <= q) ? e3 : 0.0f;
        }
        lsum[r] += (e0 + e1) + (e2 + e3);
        const int prow = (lq * 4 + r) * 72;
        lPw[prow + lr]      = f2bf_pos(e0);
        lPw[prow + 16 + lr] = f2bf_pos(e1);
        lPw[prow + 32 + lr] = f2bf_pos(e2);
        lPw[prow + 48 + lr] = f2bf_pos(e3);
      }

      // P: C-layout -> A-layout via per-wave LDS
      asm volatile("s_waitcnt lgkmcnt(0)" ::: "memory");
      const short8 pf0 = *(const short8*)&lPw[lr * 72 + lq * 8];
      const short8 pf1 = *(const short8*)&lPw[lr * 72 + 32 + lq * 8];

      #pragma unroll
      for (int nb = 0; nb < 4; nb++){
        const short8 bv0 = *(const short8*)&lVt[(nb * 16 + lr) * 64 + lq * 8];
        const short8 bv1 = *(const short8*)&lVt[(nb * 16 + lr) * 64 + 32 + lq * 8];
        o[nb] = __builtin_amdgcn_mfma_f32_16x16x32_bf16(pf0, bv0, o[nb], 0, 0, 0);
        o[nb] = __builtin_amdgcn_mfma_f32_16x16x32_bf16(pf1, bv1, o[nb], 0, 0, 0);
      }
    }

    // one reduction tree per part: sum over the 16 key-lanes (lr)
    #pragma unroll
    for (int r = 0; r < 4; r++){
      float l = lsum[r];
      l += __shfl_xor(l, 1);
      l += __shfl_xor(l, 2);
      l += __shfl_xor(l, 4);
      l += __shfl_xor(l, 8);
      const float inv = __builtin_amdgcn_rcpf(l);
      const size_t row = (size_t)(b * CS + q0 + wave * 16 + lq * 4 + r);
      #pragma unroll
      for (int nb = 0; nb < 4; nb++)
        outp[row * CD + h * CDH + nb * 16 + lr] = f2bf(o[nb][r] * inv);
    }
  }
}

extern "C" void kernel_launch(void* const* d_in, const int* in_sizes, int n_in,
                              void* d_out, int out_size, void* d_ws, size_t ws_size,
                              hipStream_t stream)
{
  const float* x   = (const float*)d_in[0];
  const float* Wq  = (const float*)d_in[2];
  const float* Wk  = (const float*)d_in[3];
  const float* Wv  = (const float*)d_in[4];
  const float* Wo  = (const float*)d_in[5];
  const float* w1  = (const float*)d_in[6];
  const float* b1  = (const float*)d_in[7];
  const float* w2  = (const float*)d_in[8];
  const float* b2  = (const float*)d_in[9];
  const float* g1  = (const float*)d_in[10];
  const float* be1 = (const float*)d_in[11];
  const float* g2  = (const float*)d_in[12];
  const float* be2 = (const float*)d_in[13];
  float* out = (float*)d_out;

  char* ws = (char*)d_ws;
  const size_t MB = 1u << 20;
  u16* yln    = (u16*)(ws);              // [4096][1024] bf16 (also hn)       8 MB
  u16* qk     = (u16*)(ws + 8  * MB);    // [4096][2048] bf16 (Q|K)          16 MB
  u16* vt     = (u16*)(ws + 24 * MB);    // [B*H*64][2048] bf16 (V^T)         8 MB
  u16* attn   = (u16*)(ws + 32 * MB);    // [4096][1024] bf16                 8 MB
  u16* mid    = (u16*)(ws + 40 * MB);    // [4096][4096] bf16                32 MB
  u16* Wqkv_t = (u16*)(ws + 72 * MB);    // [3072][1024] bf16                 6 MB
  u16* Wo_t   = (u16*)(ws + 78 * MB);    // [1024][1024] bf16                 2 MB
  u16* w1_t   = (u16*)(ws + 80 * MB);    // [4096][1024] bf16                 8 MB
  u16* w2_t   = (u16*)(ws + 88 * MB);    // [1024][4096] bf16                 8 MB

  const int M = CB * CS;  // 4096
  const int BIG = 1 << 30;

  // weight prep: all 6 transposes in one launch
  TPAll pa;
  pa.s[0] = Wq; pa.s[1] = Wk; pa.s[2] = Wv; pa.s[3] = Wo; pa.s[4] = w1; pa.s[5] = w2;
  pa.d[0] = Wqkv_t;
  pa.d[1] = Wqkv_t + (size_t)CD * CD;
  pa.d[2] = Wqkv_t + (size_t)2 * CD * CD;
  pa.d[3] = Wo_t;
  pa.d[4] = w1_t;
  pa.d[5] = w2_t;
  transpose_all<<<3 * 4096, 256, 0, stream>>>(pa);

  // LN1: x -> yln (bf16)
  ln_bf16<0><<<M, 256, 0, stream>>>(x, g1, be1, yln, nullptr, nullptr);
  // QKV: Q,K -> qk (ldc=2048, Q pre-scaled 0.125); V -> vt (transposed)
  gemm_bt<0><<<24 * 32, 256, 0, stream>>>(yln, Wqkv_t, qk, nullptr, M, 3 * CD, CD, 2048, 2048, vt);
  // attention (grid: x=bh for XCD L2 locality, y=pair)
  attn_kernel<<<dim3(CB * CH, NQB / 2), 256, 0, stream>>>(qk, vt, attn);
  // h = x + attn @ Wo   (64x128 tiles, no atomics, resid = x)
  gemm_bt64<<<64 * 8, 256, 0, stream>>>(attn, Wo_t, x, out, M, CD, CD);
  // LN2: h -> hn (bf16); also out = h + b2 in-place (residual+bias for FFN2)
  ln_bf16<2><<<M, 256, 0, stream>>>(out, g2, be2, yln, (float4*)out, b2);
  // mid = relu(hn @ w1 + b1)
  gemm_bt<1><<<32 * 32, 256, 0, stream>>>(yln, w1_t, mid, b1, M, CDFF, CD, CDFF, BIG, nullptr);
  // out = (h + b2) + mid @ w2   (64x128 tiles, 64 k-iters, no atomics)
  gemm_bt64<<<64 * 8, 256, 0, stream>>>(mid, w2_t, out, out, M, CD, CDFF);
}

// Round 8
// 382.624 us; speedup vs baseline: 1.1364x; 1.0592x over previous
//
#include <hip/hip_runtime.h>

typedef unsigned short u16;
typedef __attribute__((ext_vector_type(8))) short short8;
typedef __attribute__((ext_vector_type(4))) float f32x4;

#define CB 2
#define CS 2048
#define CD 1024
#define CH 16
#define CDH 64
#define CDFF 4096
#define NQB (CS / 64)   // 32 q-blocks of 64

__device__ __forceinline__ u16 f2bf(float f){
  union { float f; unsigned u; } x; x.f = f;
  unsigned r = (x.u + 0x7fffu + ((x.u >> 16) & 1u)) >> 16;
  return (u16)r;
}

// cheap round for positive values (P matrix): round-half-up, 2 VALU ops
__device__ __forceinline__ u16 f2bf_pos(float f){
  union { float f; unsigned u; } x; x.f = f;
  return (u16)((x.u + 0x8000u) >> 16);
}

__device__ __forceinline__ void gload_lds16(const void* g, void* l){
  __builtin_amdgcn_global_load_lds(
    (const __attribute__((address_space(1))) void*)(unsigned long long)g,
    (__attribute__((address_space(3))) void*)(unsigned long long)l,
    16, 0, 0);
}

// ---------------- all 6 weight transposes ([K][N] f32 -> [N][K] bf16) in ONE launch
struct TPAll { const float* s[6]; u16* d[6]; };

__global__ __launch_bounds__(256)
void transpose_all(TPAll p)
{
  __shared__ float t[32][33];
  const int g = blockIdx.x >> 12;
  const int id = blockIdx.x & 4095;
  const float* __restrict__ in;
  u16* __restrict__ out;
  int K, N, n0, k0;
  if (g == 0){
    const int w = id >> 10, tile = id & 1023;
    in = p.s[w]; out = p.d[w]; K = 1024; N = 1024;
    n0 = (tile & 31) * 32; k0 = (tile >> 5) * 32;
  } else if (g == 1){
    in = p.s[4]; out = p.d[4]; K = 1024; N = 4096;
    n0 = (id & 127) * 32; k0 = (id >> 7) * 32;
  } else {
    in = p.s[5]; out = p.d[5]; K = 4096; N = 1024;
    n0 = (id & 31) * 32; k0 = (id >> 5) * 32;
  }
  const int c = threadIdx.x & 31, r4 = threadIdx.x >> 5;
  #pragma unroll
  for (int i = 0; i < 4; i++){
    int r = r4 + i * 8;
    t[r][c] = in[(size_t)(k0 + r) * N + n0 + c];
  }
  __syncthreads();
  #pragma unroll
  for (int i = 0; i < 4; i++){
    int r = r4 + i * 8;
    out[(size_t)(n0 + r) * K + k0 + c] = f2bf(t[c][r]);
  }
}

// ---------------- LayerNorm: fp32 row [1024] -> bf16 row, one block per row
// MODE 0: LN only.  MODE 2: also write aux = v + bias (fp32, may alias xin)
template<int MODE>
__global__ __launch_bounds__(256)
void ln_bf16(const float* __restrict__ xin, const float* __restrict__ g,
             const float* __restrict__ be, u16* __restrict__ outp,
             float4* __restrict__ aux, const float* __restrict__ bias)
{
  const int row = blockIdx.x, tid = threadIdx.x;
  const int lane = tid & 63, wave = tid >> 6;
  const float4 v = ((const float4*)(xin + (size_t)row * CD))[tid];
  float s  = v.x + v.y + v.z + v.w;
  float s2 = v.x*v.x + v.y*v.y + v.z*v.z + v.w*v.w;
  #pragma unroll
  for (int m = 1; m < 64; m <<= 1){ s += __shfl_xor(s, m); s2 += __shfl_xor(s2, m); }
  __shared__ float red[8];
  if (lane == 0){ red[wave] = s; red[4 + wave] = s2; }

  if (MODE == 2){
    const float4 b4 = ((const float4*)bias)[tid];
    float4 w = v;
    w.x += b4.x; w.y += b4.y; w.z += b4.z; w.w += b4.w;
    aux[(size_t)row * 256 + tid] = w;
  }

  __syncthreads();
  s  = red[0] + red[1] + red[2] + red[3];
  s2 = red[4] + red[5] + red[6] + red[7];
  const float mu = s * (1.0f / CD);
  const float var = s2 * (1.0f / CD) - mu * mu;
  const float rs = rsqrtf(var + 1e-5f);
  const float4 gv = ((const float4*)g)[tid];
  const float4 bv = ((const float4*)be)[tid];
  ushort4 o;
  o.x = f2bf((v.x - mu) * rs * gv.x + bv.x);
  o.y = f2bf((v.y - mu) * rs * gv.y + bv.y);
  o.z = f2bf((v.z - mu) * rs * gv.z + bv.z);
  o.w = f2bf((v.w - mu) * rs * gv.w + bv.w);
  ((ushort4*)outp)[(size_t)row * (CD / 4) + tid] = o;
}

// ---------------- GEMM 128x128: C[M,N] = A[M,K] (bf16) * Bt[N,K]^T (bf16)
// 1-D grid, XCD-banded swizzle. EPI 0 (QKV): store bf16, Q pre-scaled 0.125,
// n0>=vsplit -> V^T.  EPI 1: +bias, relu, store bf16.
template<int EPI>
__global__ __launch_bounds__(256)
void gemm_bt(const u16* __restrict__ A, const u16* __restrict__ Bt,
             void* __restrict__ Cout, const float* __restrict__ bias,
             int M, int N, int K,
             int ldc, int vsplit, u16* __restrict__ vtout)
{
  __shared__ __align__(16) u16 lA[128 * 64];
  __shared__ __align__(16) u16 lB[128 * 64];
  const int tid = threadIdx.x;
  const int wave = tid >> 6, lane = tid & 63;

  // XCD-banded tile decode (n-fastest)
  const int G = gridDim.x;
  const int flat = blockIdx.x;
  const int t = (flat & 7) * (G >> 3) + (flat >> 3);
  const int NN = N >> 7;
  const int n_i = t % NN;
  const int m_i = t / NN;

  const int m0 = m_i * 128, n0 = n_i * 128;
  const int wm = (wave >> 1) * 64, wn = (wave & 1) * 64;
  const int lq = lane >> 4, lr = lane & 15;

  f32x4 acc[4][4] = {};

  const u16* Ab = A + (size_t)m0 * K;
  const u16* Bb = Bt + (size_t)n0 * K;
  const int srow = lane >> 3;          // 0..7 within a 1KB chunk
  const int scol = (lane & 7) * 8;

  for (int k0 = 0; k0 < K; k0 += 64){
    __syncthreads();
    #pragma unroll
    for (int i = 0; i < 4; i++){
      const int c = i * 4 + wave;          // chunk 0..15 (1 KB each)
      const int row = c * 8 + srow;
      gload_lds16(Ab + (size_t)row * K + k0 + scol, &lA[c * 512]);
      gload_lds16(Bb + (size_t)row * K + k0 + scol, &lB[c * 512]);
    }
    __syncthreads();
    #pragma unroll
    for (int kk = 0; kk < 64; kk += 32){
      short8 aF[4], bF[4];
      #pragma unroll
      for (int i = 0; i < 4; i++) aF[i] = *(const short8*)&lA[(wm + i * 16 + lr) * 64 + kk + lq * 8];
      #pragma unroll
      for (int j = 0; j < 4; j++) bF[j] = *(const short8*)&lB[(wn + j * 16 + lr) * 64 + kk + lq * 8];
      #pragma unroll
      for (int i = 0; i < 4; i++)
        #pragma unroll
        for (int j = 0; j < 4; j++)
          acc[i][j] = __builtin_amdgcn_mfma_f32_16x16x32_bf16(aF[i], bF[j], acc[i][j], 0, 0, 0);
    }
  }

  if (EPI == 0 && n0 >= vsplit){
    // V block: store transposed into vt[(b*16+h)*64+d][s], s = 4 consecutive rows
    #pragma unroll
    for (int i = 0; i < 4; i++){
      const int row0 = m0 + wm + i * 16 + lq * 4;
      const int bb = row0 >> 11, s = row0 & 2047;
      #pragma unroll
      for (int j = 0; j < 4; j++){
        const int col = n0 - vsplit + wn + j * 16 + lr;  // 0..1023 = h*64+d
        ushort4 o;
        o.x = f2bf(acc[i][j][0]); o.y = f2bf(acc[i][j][1]);
        o.z = f2bf(acc[i][j][2]); o.w = f2bf(acc[i][j][3]);
        *(ushort4*)&vtout[((size_t)(bb * 1024 + col)) * CS + s] = o;
      }
    }
    return;
  }

  // Q pre-scale for attention (EPI 0 / QKV only): cols < 1024 are Q
  const float osc = (EPI == 0 && n0 < 1024) ? 0.125f : 1.0f;

  #pragma unroll
  for (int i = 0; i < 4; i++){
    const int row = m0 + wm + i * 16 + lq * 4;
    #pragma unroll
    for (int j = 0; j < 4; j++){
      const int col = n0 + wn + j * 16 + lr;
      #pragma unroll
      for (int r = 0; r < 4; r++){
        float v = acc[i][j][r];
        const size_t off = (size_t)(row + r) * ldc + col;
        if (EPI == 0){
          ((u16*)Cout)[off] = f2bf(v * osc);
        } else {
          v += bias[col]; v = v > 0.0f ? v : 0.0f;
          ((u16*)Cout)[off] = f2bf(v);
        }
      }
    }
  }
}

// ---------------- GEMM 64x128, double-buffered LDS + manual vmcnt barriers:
// Cout[M,N] (f32) = resid[M,N] (f32) + A[M,K] (bf16) * Bt[N,K]^T
// Prefetch stays in flight across the barrier (s_waitcnt vmcnt(6), never 0
// except the last tile) — the AITER-style pipeline the 2-__syncthreads
// structure can't express. 48 KB LDS; grid-limited to 2 blocks/CU anyway.
__global__ __launch_bounds__(256)
void gemm_bt64(const u16* __restrict__ A, const u16* __restrict__ Bt,
               const float* __restrict__ resid, float* __restrict__ Cout,
               int M, int N, int K)
{
  __shared__ __align__(16) u16 lA[2][64 * 64];    // 16 KB
  __shared__ __align__(16) u16 lB[2][128 * 64];   // 32 KB
  const int tid = threadIdx.x;
  const int wave = tid >> 6, lane = tid & 63;

  const int G = gridDim.x;
  const int flat = blockIdx.x;
  const int t = (flat & 7) * (G >> 3) + (flat >> 3);
  const int NN = N >> 7;
  const int n_i = t % NN;
  const int m_i = t / NN;
  const int m0 = m_i * 64, n0 = n_i * 128;
  const int lq = lane >> 4, lr = lane & 15;

  f32x4 acc[4][2] = {};

  const u16* Ab = A + (size_t)m0 * K;
  const u16* Bb = Bt + (size_t)n0 * K;
  const int srow = lane >> 3, scol = (lane & 7) * 8;

  auto stage = [&](int buf, int kt){
    const int k0 = kt * 64;
    #pragma unroll
    for (int i = 0; i < 6; i++){
      const int c = i * 4 + wave;          // 0..23: chunks 0-7 = A, 8-23 = B
      if (c < 8){
        gload_lds16(Ab + (size_t)(c * 8 + srow) * K + k0 + scol, &lA[buf][c * 512]);
      } else {
        const int cb2 = c - 8;
        gload_lds16(Bb + (size_t)(cb2 * 8 + srow) * K + k0 + scol, &lB[buf][cb2 * 512]);
      }
    }
  };

  const int nit = K >> 6;
  stage(0, 0);
  for (int i = 0; i < nit; i++){
    const int cb = i & 1;
    if (i + 1 < nit){
      stage(cb ^ 1, i + 1);
      // wait for current tile's 6 loads (FIFO: oldest retire first); keep the
      // 6 prefetch loads in flight across the barrier.
      asm volatile("s_waitcnt vmcnt(6)\n\ts_barrier" ::: "memory");
    } else {
      asm volatile("s_waitcnt vmcnt(0)\n\ts_barrier" ::: "memory");
    }
    #pragma unroll
    for (int kk = 0; kk < 64; kk += 32){
      short8 aF[4], bF[2];
      #pragma unroll
      for (int i2 = 0; i2 < 4; i2++) aF[i2] = *(const short8*)&lA[cb][(i2 * 16 + lr) * 64 + kk + lq * 8];
      #pragma unroll
      for (int j = 0; j < 2; j++) bF[j] = *(const short8*)&lB[cb][(wave * 32 + j * 16 + lr) * 64 + kk + lq * 8];
      #pragma unroll
      for (int i2 = 0; i2 < 4; i2++)
        #pragma unroll
        for (int j = 0; j < 2; j++)
          acc[i2][j] = __builtin_amdgcn_mfma_f32_16x16x32_bf16(aF[i2], bF[j], acc[i2][j], 0, 0, 0);
    }
    // protect this buffer from being overwritten by iter i+2's stage
    asm volatile("s_barrier" ::: "memory");
  }

  #pragma unroll
  for (int i = 0; i < 4; i++){
    const int row = m0 + i * 16 + lq * 4;
    #pragma unroll
    for (int j = 0; j < 2; j++){
      const int col = n0 + wave * 32 + j * 16 + lr;
      #pragma unroll
      for (int r = 0; r < 4; r++){
        const size_t off = (size_t)(row + r) * N + col;
        Cout[off] = resid[off] + acc[i][j][r];
      }
    }
  }
}

// ---------------- causal flash attention, balanced q-block pairs, 64-key tiles
// Double-buffered KV staging with manual vmcnt barriers (same pipeline as
// gemm_bt64). Grid: x = bh (XCD L2 locality), y = pair. No running max;
// Q pre-scaled by 0.125.
// qk: bf16 [B*S][2048] (Q | K), vt: bf16 [B*H*DH][S], out: bf16 [B*S][1024]
__global__ __launch_bounds__(256)
void attn_kernel(const u16* __restrict__ qk, const u16* __restrict__ vt,
                 u16* __restrict__ outp)
{
  __shared__ __align__(16) u16 lK[2][64 * 64];   // [key][d]  16 KB
  __shared__ __align__(16) u16 lVt[2][64 * 64];  // [d][key]  16 KB
  __shared__ __align__(16) u16 lP[4][16 * 72];   // per-wave P, padded  9 KB
  const int tid = threadIdx.x, wave = tid >> 6, lane = tid & 63;
  const int lq = lane >> 4, lr = lane & 15;
  const int bh = blockIdx.x, b = bh >> 4, h = bh & 15;
  const int RS = 2048;
  const int srow = lane >> 3, scol = (lane & 7) * 8;

  const size_t kbase = (size_t)(b * CS) * RS + 1024 + h * CDH;
  const size_t vbase = (size_t)(bh * CDH) * CS;
  u16* lPw = lP[wave];

  auto stageKV = [&](int buf, int kt){
    #pragma unroll
    for (int cc = 0; cc < 2; cc++){
      const int c = wave * 2 + cc;             // chunk 0..7, 8 rows each
      gload_lds16(qk + kbase + (size_t)(kt * 64 + c * 8 + srow) * RS + scol, &lK[buf][c * 512]);
      gload_lds16(vt + vbase + (size_t)(c * 8 + srow) * CS + kt * 64 + scol, &lVt[buf][c * 512]);
    }
  };

  #pragma unroll 1
  for (int part = 0; part < 2; part++){
    const int iq = part ? (NQB - 1 - blockIdx.y) : blockIdx.y;
    const int q0 = iq * 64;
    const int ktmax = iq + 1;

    // Q fragments (A-layout): m = lr, k = lq*8 + j (+32); already * 0.125
    const int qrow = b * CS + q0 + wave * 16 + lr;
    const u16* qp = qk + (size_t)qrow * RS + h * CDH;
    const short8 qf0 = *(const short8*)(qp + lq * 8);
    const short8 qf1 = *(const short8*)(qp + 32 + lq * 8);

    f32x4 o[4] = {};
    float lsum[4] = {0.0f, 0.0f, 0.0f, 0.0f};

    stageKV(0, 0);
    for (int kt = 0; kt < ktmax; ++kt){
      const int cb = kt & 1;
      if (kt + 1 < ktmax){
        stageKV(cb ^ 1, kt + 1);
        asm volatile("s_waitcnt vmcnt(4)\n\ts_barrier" ::: "memory");
      } else {
        asm volatile("s_waitcnt vmcnt(0)\n\ts_barrier" ::: "memory");
      }

      // S = Q K^T : 16 q-rows x 64 keys (pre-scaled)
      f32x4 s[4] = {};
      #pragma unroll
      for (int nb = 0; nb < 4; nb++){
        const short8 bk0 = *(const short8*)&lK[cb][(nb * 16 + lr) * 64 + lq * 8];
        const short8 bk1 = *(const short8*)&lK[cb][(nb * 16 + lr) * 64 + 32 + lq * 8];
        s[nb] = __builtin_amdgcn_mfma_f32_16x16x32_bf16(qf0, bk0, s[nb], 0, 0, 0);
        s[nb] = __builtin_amdgcn_mfma_f32_16x16x32_bf16(qf1, bk1, s[nb], 0, 0, 0);
      }

      const bool diag = (kt + 1) == ktmax;       // only diagonal tile needs mask
      const int qg = q0 + wave * 16 + lq * 4;
      #pragma unroll
      for (int r = 0; r < 4; r++){
        float e0 = __expf(s[0][r]);
        float e1 = __expf(s[1][r]);
        float e2 = __expf(s[2][r]);
        float e3 = __expf(s[3][r]);
        if (diag){
          const int q = qg + r, kb = kt * 64 + lr;
          e0 = (kb      <= q) ? e0 : 0.0f;
          e1 = (kb + 16 <= q) ? e1 : 0.0f;
          e2 = (kb + 32 <= q) ? e2 : 0.0f;
          e3 = (kb + 48 <= q) ? e3 : 0.0f;
        }
        lsum[r] += (e0 + e1) + (e2 + e3);
        const int prow = (lq * 4 + r) * 72;
        lPw[prow + lr]      = f2bf_pos(e0);
        lPw[prow + 16 + lr] = f2bf_pos(e1);
        lPw[prow + 32 + lr] = f2bf_pos(e2);
        lPw[prow + 48 + lr] = f2bf_pos(e3);
      }

      // P: C-layout -> A-layout via per-wave LDS
      asm volatile("s_waitcnt lgkmcnt(0)" ::: "memory");
      const short8 pf0 = *(const short8*)&lPw[lr * 72 + lq * 8];
      const short8 pf1 = *(const short8*)&lPw[lr * 72 + 32 + lq * 8];

      #pragma unroll
      for (int nb = 0; nb < 4; nb++){
        const short8 bv0 = *(const short8*)&lVt[cb][(nb * 16 + lr) * 64 + lq * 8];
        const short8 bv1 = *(const short8*)&lVt[cb][(nb * 16 + lr) * 64 + 32 + lq * 8];
        o[nb] = __builtin_amdgcn_mfma_f32_16x16x32_bf16(pf0, bv0, o[nb], 0, 0, 0);
        o[nb] = __builtin_amdgcn_mfma_f32_16x16x32_bf16(pf1, bv1, o[nb], 0, 0, 0);
      }
      // protect buffer cb from overwrite by kt+2's stage
      asm volatile("s_barrier" ::: "memory");
    }

    // one reduction tree per part: sum over the 16 key-lanes (lr)
    #pragma unroll
    for (int r = 0; r < 4; r++){
      float l = lsum[r];
      l += __shfl_xor(l, 1);
      l += __shfl_xor(l, 2);
      l += __shfl_xor(l, 4);
      l += __shfl_xor(l, 8);
      const float inv = __builtin_amdgcn_rcpf(l);
      const size_t row = (size_t)(b * CS + q0 + wave * 16 + lq * 4 + r);
      #pragma unroll
      for (int nb = 0; nb < 4; nb++)
        outp[row * CD + h * CDH + nb * 16 + lr] = f2bf(o[nb][r] * inv);
    }
  }
}

extern "C" void kernel_launch(void* const* d_in, const int* in_sizes, int n_in,
                              void* d_out, int out_size, void* d_ws, size_t ws_size,
                              hipStream_t stream)
{
  const float* x   = (const float*)d_in[0];
  const float* Wq  = (const float*)d_in[2];
  const float* Wk  = (const float*)d_in[3];
  const float* Wv  = (const float*)d_in[4];
  const float* Wo  = (const float*)d_in[5];
  const float* w1  = (const float*)d_in[6];
  const float* b1  = (const float*)d_in[7];
  const float* w2  = (const float*)d_in[8];
  const float* b2  = (const float*)d_in[9];
  const float* g1  = (const float*)d_in[10];
  const float* be1 = (const float*)d_in[11];
  const float* g2  = (const float*)d_in[12];
  const float* be2 = (const float*)d_in[13];
  float* out = (float*)d_out;

  char* ws = (char*)d_ws;
  const size_t MB = 1u << 20;
  u16* yln    = (u16*)(ws);              // [4096][1024] bf16 (also hn)       8 MB
  u16* qk     = (u16*)(ws + 8  * MB);    // [4096][2048] bf16 (Q|K)          16 MB
  u16* vt     = (u16*)(ws + 24 * MB);    // [B*H*64][2048] bf16 (V^T)         8 MB
  u16* attn   = (u16*)(ws + 32 * MB);    // [4096][1024] bf16                 8 MB
  u16* mid    = (u16*)(ws + 40 * MB);    // [4096][4096] bf16                32 MB
  u16* Wqkv_t = (u16*)(ws + 72 * MB);    // [3072][1024] bf16                 6 MB
  u16* Wo_t   = (u16*)(ws + 78 * MB);    // [1024][1024] bf16                 2 MB
  u16* w1_t   = (u16*)(ws + 80 * MB);    // [4096][1024] bf16                 8 MB
  u16* w2_t   = (u16*)(ws + 88 * MB);    // [1024][4096] bf16                 8 MB

  const int M = CB * CS;  // 4096
  const int BIG = 1 << 30;

  // weight prep: all 6 transposes in one launch
  TPAll pa;
  pa.s[0] = Wq; pa.s[1] = Wk; pa.s[2] = Wv; pa.s[3] = Wo; pa.s[4] = w1; pa.s[5] = w2;
  pa.d[0] = Wqkv_t;
  pa.d[1] = Wqkv_t + (size_t)CD * CD;
  pa.d[2] = Wqkv_t + (size_t)2 * CD * CD;
  pa.d[3] = Wo_t;
  pa.d[4] = w1_t;
  pa.d[5] = w2_t;
  transpose_all<<<3 * 4096, 256, 0, stream>>>(pa);

  // LN1: x -> yln (bf16)
  ln_bf16<0><<<M, 256, 0, stream>>>(x, g1, be1, yln, nullptr, nullptr);
  // QKV: Q,K -> qk (ldc=2048, Q pre-scaled 0.125); V -> vt (transposed)
  gemm_bt<0><<<24 * 32, 256, 0, stream>>>(yln, Wqkv_t, qk, nullptr, M, 3 * CD, CD, 2048, 2048, vt);
  // attention (grid: x=bh for XCD L2 locality, y=pair)
  attn_kernel<<<dim3(CB * CH, NQB / 2), 256, 0, stream>>>(qk, vt, attn);
  // h = x + attn @ Wo   (64x128 tiles, dbuf pipeline, resid = x)
  gemm_bt64<<<64 * 8, 256, 0, stream>>>(attn, Wo_t, x, out, M, CD, CD);
  // LN2: h -> hn (bf16); also out = h + b2 in-place (residual+bias for FFN2)
  ln_bf16<2><<<M, 256, 0, stream>>>(out, g2, be2, yln, (float4*)out, b2);
  // mid = relu(hn @ w1 + b1)
  gemm_bt<1><<<32 * 32, 256, 0, stream>>>(yln, w1_t, mid, b1, M, CDFF, CD, CDFF, BIG, nullptr);
  // out = (h + b2) + mid @ w2   (64x128 tiles, dbuf pipeline, 64 k-iters)
  gemm_bt64<<<64 * 8, 256, 0, stream>>>(mid, w2_t, out, out, M, CD, CDFF);
}

// Round 9
// 355.906 us; speedup vs baseline: 1.2217x; 1.0751x over previous
//
#include <hip/hip_runtime.h>

typedef unsigned short u16;
typedef __attribute__((ext_vector_type(8))) short short8;
typedef __attribute__((ext_vector_type(4))) float f32x4;

#define CB 2
#define CS 2048
#define CD 1024
#define CH 16
#define CDH 64
#define CDFF 4096
#define NQB (CS / 64)   // 32 q-blocks of 64

__device__ __forceinline__ u16 f2bf(float f){
  union { float f; unsigned u; } x; x.f = f;
  unsigned r = (x.u + 0x7fffu + ((x.u >> 16) & 1u)) >> 16;
  return (u16)r;
}

// cheap round for positive values (P matrix): round-half-up, 2 VALU ops
__device__ __forceinline__ u16 f2bf_pos(float f){
  union { float f; unsigned u; } x; x.f = f;
  return (u16)((x.u + 0x8000u) >> 16);
}

__device__ __forceinline__ void gload_lds16(const void* g, void* l){
  __builtin_amdgcn_global_load_lds(
    (const __attribute__((address_space(1))) void*)(unsigned long long)g,
    (__attribute__((address_space(3))) void*)(unsigned long long)l,
    16, 0, 0);
}

// ---------------- fused prep: all 6 weight transposes + LN1, one launch
// blocks 0..4095: Wq,Wk,Wv,Wo tiles; 4096..8191: w1; 8192..12287: w2;
// 12288..16383: LN1 rows (x -> yln bf16)
struct TPAll { const float* s[6]; u16* d[6]; };

__global__ __launch_bounds__(256)
void prep_all(TPAll p, const float* __restrict__ x, const float* __restrict__ g1,
              const float* __restrict__ be1, u16* __restrict__ yln)
{
  const int g = blockIdx.x >> 12;
  const int id = blockIdx.x & 4095;
  const int tid = threadIdx.x;

  if (g == 3){
    // ---- LN1 row
    const int row = id;
    const int lane = tid & 63, wave = tid >> 6;
    const float4 v = ((const float4*)(x + (size_t)row * CD))[tid];
    float s  = v.x + v.y + v.z + v.w;
    float s2 = v.x*v.x + v.y*v.y + v.z*v.z + v.w*v.w;
    #pragma unroll
    for (int m = 1; m < 64; m <<= 1){ s += __shfl_xor(s, m); s2 += __shfl_xor(s2, m); }
    __shared__ float red[8];
    if (lane == 0){ red[wave] = s; red[4 + wave] = s2; }
    __syncthreads();
    s  = red[0] + red[1] + red[2] + red[3];
    s2 = red[4] + red[5] + red[6] + red[7];
    const float mu = s * (1.0f / CD);
    const float var = s2 * (1.0f / CD) - mu * mu;
    const float rs = rsqrtf(var + 1e-5f);
    const float4 gv = ((const float4*)g1)[tid];
    const float4 bv = ((const float4*)be1)[tid];
    ushort4 o;
    o.x = f2bf((v.x - mu) * rs * gv.x + bv.x);
    o.y = f2bf((v.y - mu) * rs * gv.y + bv.y);
    o.z = f2bf((v.z - mu) * rs * gv.z + bv.z);
    o.w = f2bf((v.w - mu) * rs * gv.w + bv.w);
    ((ushort4*)yln)[(size_t)row * (CD / 4) + tid] = o;
    return;
  }

  // ---- transpose tile
  __shared__ float t[32][33];
  const float* __restrict__ in;
  u16* __restrict__ out;
  int K, N, n0, k0;
  if (g == 0){
    const int w = id >> 10, tile = id & 1023;
    in = p.s[w]; out = p.d[w]; K = 1024; N = 1024;
    n0 = (tile & 31) * 32; k0 = (tile >> 5) * 32;
  } else if (g == 1){
    in = p.s[4]; out = p.d[4]; K = 1024; N = 4096;
    n0 = (id & 127) * 32; k0 = (id >> 7) * 32;
  } else {
    in = p.s[5]; out = p.d[5]; K = 4096; N = 1024;
    n0 = (id & 31) * 32; k0 = (id >> 5) * 32;
  }
  const int c = tid & 31, r4 = tid >> 5;
  #pragma unroll
  for (int i = 0; i < 4; i++){
    int r = r4 + i * 8;
    t[r][c] = in[(size_t)(k0 + r) * N + n0 + c];
  }
  __syncthreads();
  #pragma unroll
  for (int i = 0; i < 4; i++){
    int r = r4 + i * 8;
    out[(size_t)(n0 + r) * K + k0 + c] = f2bf(t[c][r]);
  }
}

// ---------------- LayerNorm: fp32 row [1024] -> bf16 row, one block per row
// MODE 0: LN only.  MODE 2: also write aux = v + bias (fp32, may alias xin)
template<int MODE>
__global__ __launch_bounds__(256)
void ln_bf16(const float* __restrict__ xin, const float* __restrict__ g,
             const float* __restrict__ be, u16* __restrict__ outp,
             float4* __restrict__ aux, const float* __restrict__ bias)
{
  const int row = blockIdx.x, tid = threadIdx.x;
  const int lane = tid & 63, wave = tid >> 6;
  const float4 v = ((const float4*)(xin + (size_t)row * CD))[tid];
  float s  = v.x + v.y + v.z + v.w;
  float s2 = v.x*v.x + v.y*v.y + v.z*v.z + v.w*v.w;
  #pragma unroll
  for (int m = 1; m < 64; m <<= 1){ s += __shfl_xor(s, m); s2 += __shfl_xor(s2, m); }
  __shared__ float red[8];
  if (lane == 0){ red[wave] = s; red[4 + wave] = s2; }

  if (MODE == 2){
    const float4 b4 = ((const float4*)bias)[tid];
    float4 w = v;
    w.x += b4.x; w.y += b4.y; w.z += b4.z; w.w += b4.w;
    aux[(size_t)row * 256 + tid] = w;
  }

  __syncthreads();
  s  = red[0] + red[1] + red[2] + red[3];
  s2 = red[4] + red[5] + red[6] + red[7];
  const float mu = s * (1.0f / CD);
  const float var = s2 * (1.0f / CD) - mu * mu;
  const float rs = rsqrtf(var + 1e-5f);
  const float4 gv = ((const float4*)g)[tid];
  const float4 bv = ((const float4*)be)[tid];
  ushort4 o;
  o.x = f2bf((v.x - mu) * rs * gv.x + bv.x);
  o.y = f2bf((v.y - mu) * rs * gv.y + bv.y);
  o.z = f2bf((v.z - mu) * rs * gv.z + bv.z);
  o.w = f2bf((v.w - mu) * rs * gv.w + bv.w);
  ((ushort4*)outp)[(size_t)row * (CD / 4) + tid] = o;
}

// ---------------- GEMM 128x128, double-buffered LDS + manual vmcnt barriers.
// 1-D grid, XCD-banded swizzle. Prefetch stays in flight across the barrier
// (s_waitcnt vmcnt(8), never 0 except last tile). 64 KB LDS -> 2 blocks/CU.
// EPI 0 (QKV): store bf16, Q pre-scaled 0.125, n0>=vsplit -> V^T.
// EPI 1: +bias, relu, store bf16.
template<int EPI>
__global__ __launch_bounds__(256)
void gemm_bt(const u16* __restrict__ A, const u16* __restrict__ Bt,
             void* __restrict__ Cout, const float* __restrict__ bias,
             int M, int N, int K,
             int ldc, int vsplit, u16* __restrict__ vtout)
{
  __shared__ __align__(16) u16 lA[2][128 * 64];   // 32 KB
  __shared__ __align__(16) u16 lB[2][128 * 64];   // 32 KB
  const int tid = threadIdx.x;
  const int wave = tid >> 6, lane = tid & 63;

  // XCD-banded tile decode (n-fastest)
  const int G = gridDim.x;
  const int flat = blockIdx.x;
  const int t = (flat & 7) * (G >> 3) + (flat >> 3);
  const int NN = N >> 7;
  const int n_i = t % NN;
  const int m_i = t / NN;

  const int m0 = m_i * 128, n0 = n_i * 128;
  const int wm = (wave >> 1) * 64, wn = (wave & 1) * 64;
  const int lq = lane >> 4, lr = lane & 15;

  f32x4 acc[4][4] = {};

  const u16* Ab = A + (size_t)m0 * K;
  const u16* Bb = Bt + (size_t)n0 * K;
  const int srow = lane >> 3;          // 0..7 within a 1KB chunk
  const int scol = (lane & 7) * 8;

  auto stage = [&](int buf, int k0){
    #pragma unroll
    for (int i = 0; i < 4; i++){
      const int c = i * 4 + wave;          // chunk 0..15 (1 KB each)
      const int row = c * 8 + srow;
      gload_lds16(Ab + (size_t)row * K + k0 + scol, &lA[buf][c * 512]);
      gload_lds16(Bb + (size_t)row * K + k0 + scol, &lB[buf][c * 512]);
    }
  };

  const int nit = K >> 6;
  stage(0, 0);
  for (int i = 0; i < nit; i++){
    const int cb = i & 1;
    if (i + 1 < nit){
      stage(cb ^ 1, (i + 1) * 64);
      // wait for current tile's 8 loads; keep the 8 prefetch loads in flight
      asm volatile("s_waitcnt vmcnt(8)\n\ts_barrier" ::: "memory");
    } else {
      asm volatile("s_waitcnt vmcnt(0)\n\ts_barrier" ::: "memory");
    }
    #pragma unroll
    for (int kk = 0; kk < 64; kk += 32){
      short8 aF[4], bF[4];
      #pragma unroll
      for (int i2 = 0; i2 < 4; i2++) aF[i2] = *(const short8*)&lA[cb][(wm + i2 * 16 + lr) * 64 + kk + lq * 8];
      #pragma unroll
      for (int j = 0; j < 4; j++) bF[j] = *(const short8*)&lB[cb][(wn + j * 16 + lr) * 64 + kk + lq * 8];
      #pragma unroll
      for (int i2 = 0; i2 < 4; i2++)
        #pragma unroll
        for (int j = 0; j < 4; j++)
          acc[i2][j] = __builtin_amdgcn_mfma_f32_16x16x32_bf16(aF[i2], bF[j], acc[i2][j], 0, 0, 0);
    }
    // protect this buffer from being overwritten by iter i+2's stage
    asm volatile("s_barrier" ::: "memory");
  }

  if (EPI == 0 && n0 >= vsplit){
    // V block: store transposed into vt[(b*16+h)*64+d][s], s = 4 consecutive rows
    #pragma unroll
    for (int i = 0; i < 4; i++){
      const int row0 = m0 + wm + i * 16 + lq * 4;
      const int bb = row0 >> 11, s = row0 & 2047;
      #pragma unroll
      for (int j = 0; j < 4; j++){
        const int col = n0 - vsplit + wn + j * 16 + lr;  // 0..1023 = h*64+d
        ushort4 o;
        o.x = f2bf(acc[i][j][0]); o.y = f2bf(acc[i][j][1]);
        o.z = f2bf(acc[i][j][2]); o.w = f2bf(acc[i][j][3]);
        *(ushort4*)&vtout[((size_t)(bb * 1024 + col)) * CS + s] = o;
      }
    }
    return;
  }

  // Q pre-scale for attention (EPI 0 / QKV only): cols < 1024 are Q
  const float osc = (EPI == 0 && n0 < 1024) ? 0.125f : 1.0f;

  #pragma unroll
  for (int i = 0; i < 4; i++){
    const int row = m0 + wm + i * 16 + lq * 4;
    #pragma unroll
    for (int j = 0; j < 4; j++){
      const int col = n0 + wn + j * 16 + lr;
      #pragma unroll
      for (int r = 0; r < 4; r++){
        float v = acc[i][j][r];
        const size_t off = (size_t)(row + r) * ldc + col;
        if (EPI == 0){
          ((u16*)Cout)[off] = f2bf(v * osc);
        } else {
          v += bias[col]; v = v > 0.0f ? v : 0.0f;
          ((u16*)Cout)[off] = f2bf(v);
        }
      }
    }
  }
}

// ---------------- GEMM 64x128, double-buffered LDS + manual vmcnt barriers:
// Cout[M,N] (f32) = resid[M,N] (f32) + A[M,K] (bf16) * Bt[N,K]^T
__global__ __launch_bounds__(256)
void gemm_bt64(const u16* __restrict__ A, const u16* __restrict__ Bt,
               const float* __restrict__ resid, float* __restrict__ Cout,
               int M, int N, int K)
{
  __shared__ __align__(16) u16 lA[2][64 * 64];    // 16 KB
  __shared__ __align__(16) u16 lB[2][128 * 64];   // 32 KB
  const int tid = threadIdx.x;
  const int wave = tid >> 6, lane = tid & 63;

  const int G = gridDim.x;
  const int flat = blockIdx.x;
  const int t = (flat & 7) * (G >> 3) + (flat >> 3);
  const int NN = N >> 7;
  const int n_i = t % NN;
  const int m_i = t / NN;
  const int m0 = m_i * 64, n0 = n_i * 128;
  const int lq = lane >> 4, lr = lane & 15;

  f32x4 acc[4][2] = {};

  const u16* Ab = A + (size_t)m0 * K;
  const u16* Bb = Bt + (size_t)n0 * K;
  const int srow = lane >> 3, scol = (lane & 7) * 8;

  auto stage = [&](int buf, int kt){
    const int k0 = kt * 64;
    #pragma unroll
    for (int i = 0; i < 6; i++){
      const int c = i * 4 + wave;          // 0..23: chunks 0-7 = A, 8-23 = B
      if (c < 8){
        gload_lds16(Ab + (size_t)(c * 8 + srow) * K + k0 + scol, &lA[buf][c * 512]);
      } else {
        const int cb2 = c - 8;
        gload_lds16(Bb + (size_t)(cb2 * 8 + srow) * K + k0 + scol, &lB[buf][cb2 * 512]);
      }
    }
  };

  const int nit = K >> 6;
  stage(0, 0);
  for (int i = 0; i < nit; i++){
    const int cb = i & 1;
    if (i + 1 < nit){
      stage(cb ^ 1, i + 1);
      asm volatile("s_waitcnt vmcnt(6)\n\ts_barrier" ::: "memory");
    } else {
      asm volatile("s_waitcnt vmcnt(0)\n\ts_barrier" ::: "memory");
    }
    #pragma unroll
    for (int kk = 0; kk < 64; kk += 32){
      short8 aF[4], bF[2];
      #pragma unroll
      for (int i2 = 0; i2 < 4; i2++) aF[i2] = *(const short8*)&lA[cb][(i2 * 16 + lr) * 64 + kk + lq * 8];
      #pragma unroll
      for (int j = 0; j < 2; j++) bF[j] = *(const short8*)&lB[cb][(wave * 32 + j * 16 + lr) * 64 + kk + lq * 8];
      #pragma unroll
      for (int i2 = 0; i2 < 4; i2++)
        #pragma unroll
        for (int j = 0; j < 2; j++)
          acc[i2][j] = __builtin_amdgcn_mfma_f32_16x16x32_bf16(aF[i2], bF[j], acc[i2][j], 0, 0, 0);
    }
    asm volatile("s_barrier" ::: "memory");
  }

  #pragma unroll
  for (int i = 0; i < 4; i++){
    const int row = m0 + i * 16 + lq * 4;
    #pragma unroll
    for (int j = 0; j < 2; j++){
      const int col = n0 + wave * 32 + j * 16 + lr;
      #pragma unroll
      for (int r = 0; r < 4; r++){
        const size_t off = (size_t)(row + r) * N + col;
        Cout[off] = resid[off] + acc[i][j][r];
      }
    }
  }
}

// ---------------- causal flash attention, balanced q-block pairs, 64-key tiles
// Double-buffered KV staging with manual vmcnt barriers. Grid: x = bh
// (XCD L2 locality), y = pair. No running max; Q pre-scaled by 0.125.
// qk: bf16 [B*S][2048] (Q | K), vt: bf16 [B*H*DH][S], out: bf16 [B*S][1024]
__global__ __launch_bounds__(256)
void attn_kernel(const u16* __restrict__ qk, const u16* __restrict__ vt,
                 u16* __restrict__ outp)
{
  __shared__ __align__(16) u16 lK[2][64 * 64];   // [key][d]  16 KB
  __shared__ __align__(16) u16 lVt[2][64 * 64];  // [d][key]  16 KB
  __shared__ __align__(16) u16 lP[4][16 * 72];   // per-wave P, padded  9 KB
  const int tid = threadIdx.x, wave = tid >> 6, lane = tid & 63;
  const int lq = lane >> 4, lr = lane & 15;
  const int bh = blockIdx.x, b = bh >> 4, h = bh & 15;
  const int RS = 2048;
  const int srow = lane >> 3, scol = (lane & 7) * 8;

  const size_t kbase = (size_t)(b * CS) * RS + 1024 + h * CDH;
  const size_t vbase = (size_t)(bh * CDH) * CS;
  u16* lPw = lP[wave];

  auto stageKV = [&](int buf, int kt){
    #pragma unroll
    for (int cc = 0; cc < 2; cc++){
      const int c = wave * 2 + cc;             // chunk 0..7, 8 rows each
      gload_lds16(qk + kbase + (size_t)(kt * 64 + c * 8 + srow) * RS + scol, &lK[buf][c * 512]);
      gload_lds16(vt + vbase + (size_t)(c * 8 + srow) * CS + kt * 64 + scol, &lVt[buf][c * 512]);
    }
  };

  #pragma unroll 1
  for (int part = 0; part < 2; part++){
    const int iq = part ? (NQB - 1 - blockIdx.y) : blockIdx.y;
    const int q0 = iq * 64;
    const int ktmax = iq + 1;

    // Q fragments (A-layout): m = lr, k = lq*8 + j (+32); already * 0.125
    const int qrow = b * CS + q0 + wave * 16 + lr;
    const u16* qp = qk + (size_t)qrow * RS + h * CDH;
    const short8 qf0 = *(const short8*)(qp + lq * 8);
    const short8 qf1 = *(const short8*)(qp + 32 + lq * 8);

    f32x4 o[4] = {};
    float lsum[4] = {0.0f, 0.0f, 0.0f, 0.0f};

    stageKV(0, 0);
    for (int kt = 0; kt < ktmax; ++kt){
      const int cb = kt & 1;
      if (kt + 1 < ktmax){
        stageKV(cb ^ 1, kt + 1);
        asm volatile("s_waitcnt vmcnt(4)\n\ts_barrier" ::: "memory");
      } else {
        asm volatile("s_waitcnt vmcnt(0)\n\ts_barrier" ::: "memory");
      }

      // S = Q K^T : 16 q-rows x 64 keys (pre-scaled)
      f32x4 s[4] = {};
      #pragma unroll
      for (int nb = 0; nb < 4; nb++){
        const short8 bk0 = *(const short8*)&lK[cb][(nb * 16 + lr) * 64 + lq * 8];
        const short8 bk1 = *(const short8*)&lK[cb][(nb * 16 + lr) * 64 + 32 + lq * 8];
        s[nb] = __builtin_amdgcn_mfma_f32_16x16x32_bf16(qf0, bk0, s[nb], 0, 0, 0);
        s[nb] = __builtin_amdgcn_mfma_f32_16x16x32_bf16(qf1, bk1, s[nb], 0, 0, 0);
      }

      const bool diag = (kt + 1) == ktmax;       // only diagonal tile needs mask
      const int qg = q0 + wave * 16 + lq * 4;
      #pragma unroll
      for (int r = 0; r < 4; r++){
        float e0 = __expf(s[0][r]);
        float e1 = __expf(s[1][r]);
        float e2 = __expf(s[2][r]);
        float e3 = __expf(s[3][r]);
        if (diag){
          const int q = qg + r, kb = kt * 64 + lr;
          e0 = (kb      <= q) ? e0 : 0.0f;
          e1 = (kb + 16 <= q) ? e1 : 0.0f;
          e2 = (kb + 32 <= q) ? e2 : 0.0f;
          e3 = (kb + 48 <= q) ? e3 : 0.0f;
        }
        lsum[r] += (e0 + e1) + (e2 + e3);
        const int prow = (lq * 4 + r) * 72;
        lPw[prow + lr]      = f2bf_pos(e0);
        lPw[prow + 16 + lr] = f2bf_pos(e1);
        lPw[prow + 32 + lr] = f2bf_pos(e2);
        lPw[prow + 48 + lr] = f2bf_pos(e3);
      }

      // P: C-layout -> A-layout via per-wave LDS
      asm volatile("s_waitcnt lgkmcnt(0)" ::: "memory");
      const short8 pf0 = *(const short8*)&lPw[lr * 72 + lq * 8];
      const short8 pf1 = *(const short8*)&lPw[lr * 72 + 32 + lq * 8];

      #pragma unroll
      for (int nb = 0; nb < 4; nb++){
        const short8 bv0 = *(const short8*)&lVt[cb][(nb * 16 + lr) * 64 + lq * 8];
        const short8 bv1 = *(const short8*)&lVt[cb][(nb * 16 + lr) * 64 + 32 + lq * 8];
        o[nb] = __builtin_amdgcn_mfma_f32_16x16x32_bf16(pf0, bv0, o[nb], 0, 0, 0);
        o[nb] = __builtin_amdgcn_mfma_f32_16x16x32_bf16(pf1, bv1, o[nb], 0, 0, 0);
      }
      // protect buffer cb from overwrite by kt+2's stage
      asm volatile("s_barrier" ::: "memory");
    }

    // one reduction tree per part: sum over the 16 key-lanes (lr)
    #pragma unroll
    for (int r = 0; r < 4; r++){
      float l = lsum[r];
      l += __shfl_xor(l, 1);
      l += __shfl_xor(l, 2);
      l += __shfl_xor(l, 4);
      l += __shfl_xor(l, 8);
      const float inv = __builtin_amdgcn_rcpf(l);
      const size_t row = (size_t)(b * CS + q0 + wave * 16 + lq * 4 + r);
      #pragma unroll
      for (int nb = 0; nb < 4; nb++)
        outp[row * CD + h * CDH + nb * 16 + lr] = f2bf(o[nb][r] * inv);
    }
  }
}

extern "C" void kernel_launch(void* const* d_in, const int* in_sizes, int n_in,
                              void* d_out, int out_size, void* d_ws, size_t ws_size,
                              hipStream_t stream)
{
  const float* x   = (const float*)d_in[0];
  const float* Wq  = (const float*)d_in[2];
  const float* Wk  = (const float*)d_in[3];
  const float* Wv  = (const float*)d_in[4];
  const float* Wo  = (const float*)d_in[5];
  const float* w1  = (const float*)d_in[6];
  const float* b1  = (const float*)d_in[7];
  const float* w2  = (const float*)d_in[8];
  const float* b2  = (const float*)d_in[9];
  const float* g1  = (const float*)d_in[10];
  const float* be1 = (const float*)d_in[11];
  const float* g2  = (const float*)d_in[12];
  const float* be2 = (const float*)d_in[13];
  float* out = (float*)d_out;

  char* ws = (char*)d_ws;
  const size_t MB = 1u << 20;
  u16* yln    = (u16*)(ws);              // [4096][1024] bf16 (also hn)       8 MB
  u16* qk     = (u16*)(ws + 8  * MB);    // [4096][2048] bf16 (Q|K)          16 MB
  u16* vt     = (u16*)(ws + 24 * MB);    // [B*H*64][2048] bf16 (V^T)         8 MB
  u16* attn   = (u16*)(ws + 32 * MB);    // [4096][1024] bf16                 8 MB
  u16* mid    = (u16*)(ws + 40 * MB);    // [4096][4096] bf16                32 MB
  u16* Wqkv_t = (u16*)(ws + 72 * MB);    // [3072][1024] bf16                 6 MB
  u16* Wo_t   = (u16*)(ws + 78 * MB);    // [1024][1024] bf16                 2 MB
  u16* w1_t   = (u16*)(ws + 80 * MB);    // [4096][1024] bf16                 8 MB
  u16* w2_t   = (u16*)(ws + 88 * MB);    // [1024][4096] bf16                 8 MB

  const int M = CB * CS;  // 4096
  const int BIG = 1 << 30;

  // prep: all 6 transposes + LN1 fused in one launch
  TPAll pa;
  pa.s[0] = Wq; pa.s[1] = Wk; pa.s[2] = Wv; pa.s[3] = Wo; pa.s[4] = w1; pa.s[5] = w2;
  pa.d[0] = Wqkv_t;
  pa.d[1] = Wqkv_t + (size_t)CD * CD;
  pa.d[2] = Wqkv_t + (size_t)2 * CD * CD;
  pa.d[3] = Wo_t;
  pa.d[4] = w1_t;
  pa.d[5] = w2_t;
  prep_all<<<4 * 4096, 256, 0, stream>>>(pa, x, g1, be1, yln);

  // QKV: Q,K -> qk (ldc=2048, Q pre-scaled 0.125); V -> vt (transposed)
  gemm_bt<0><<<24 * 32, 256, 0, stream>>>(yln, Wqkv_t, qk, nullptr, M, 3 * CD, CD, 2048, 2048, vt);
  // attention (grid: x=bh for XCD L2 locality, y=pair)
  attn_kernel<<<dim3(CB * CH, NQB / 2), 256, 0, stream>>>(qk, vt, attn);
  // h = x + attn @ Wo   (64x128 tiles, dbuf pipeline, resid = x)
  gemm_bt64<<<64 * 8, 256, 0, stream>>>(attn, Wo_t, x, out, M, CD, CD);
  // LN2: h -> hn (bf16); also out = h + b2 in-place (residual+bias for FFN2)
  ln_bf16<2><<<M, 256, 0, stream>>>(out, g2, be2, yln, (float4*)out, b2);
  // mid = relu(hn @ w1 + b1)  (128x128 dbuf pipeline)
  gemm_bt<1><<<32 * 32, 256, 0, stream>>>(yln, w1_t, mid, b1, M, CDFF, CD, CDFF, BIG, nullptr);
  // out = (h + b2) + mid @ w2   (64x128 tiles, dbuf pipeline, 64 k-iters)
  gemm_bt64<<<64 * 8, 256, 0, stream>>>(mid, w2_t, out, out, M, CD, CDFF);
}

// Round 10
// 315.384 us; speedup vs baseline: 1.3787x; 1.1285x over previous
//
#include <hip/hip_runtime.h>

typedef unsigned short u16;
typedef __attribute__((ext_vector_type(8))) short short8;
typedef __attribute__((ext_vector_type(4))) float f32x4;

#define CB 2
#define CS 2048
#define CD 1024
#define CH 16
#define CDH 64
#define CDFF 4096
#define NQB (CS / 64)   // 32 q-blocks of 64

__device__ __forceinline__ u16 f2bf(float f){
  union { float f; unsigned u; } x; x.f = f;
  unsigned r = (x.u + 0x7fffu + ((x.u >> 16) & 1u)) >> 16;
  return (u16)r;
}

// cheap round for positive values (P matrix): round-half-up, 2 VALU ops
__device__ __forceinline__ u16 f2bf_pos(float f){
  union { float f; unsigned u; } x; x.f = f;
  return (u16)((x.u + 0x8000u) >> 16);
}

__device__ __forceinline__ void gload_lds16(const void* g, void* l){
  __builtin_amdgcn_global_load_lds(
    (const __attribute__((address_space(1))) void*)(unsigned long long)g,
    (__attribute__((address_space(3))) void*)(unsigned long long)l,
    16, 0, 0);
}

// LDS XOR swizzle: LDS 8-elem block j of row r holds global block j^(r&7).
// Staging loads global col block (lane&7)^srow; fragment reads XOR with lr&7.
// Kills the 16-way bank conflict of the row-stride-128B layout.

// ---------------- fused prep: all 6 weight transposes + LN1, one launch
struct TPAll { const float* s[6]; u16* d[6]; };

__global__ __launch_bounds__(256)
void prep_all(TPAll p, const float* __restrict__ x, const float* __restrict__ g1,
              const float* __restrict__ be1, u16* __restrict__ yln)
{
  const int g = blockIdx.x >> 12;
  const int id = blockIdx.x & 4095;
  const int tid = threadIdx.x;

  if (g == 3){
    // ---- LN1 row
    const int row = id;
    const int lane = tid & 63, wave = tid >> 6;
    const float4 v = ((const float4*)(x + (size_t)row * CD))[tid];
    float s  = v.x + v.y + v.z + v.w;
    float s2 = v.x*v.x + v.y*v.y + v.z*v.z + v.w*v.w;
    #pragma unroll
    for (int m = 1; m < 64; m <<= 1){ s += __shfl_xor(s, m); s2 += __shfl_xor(s2, m); }
    __shared__ float red[8];
    if (lane == 0){ red[wave] = s; red[4 + wave] = s2; }
    __syncthreads();
    s  = red[0] + red[1] + red[2] + red[3];
    s2 = red[4] + red[5] + red[6] + red[7];
    const float mu = s * (1.0f / CD);
    const float var = s2 * (1.0f / CD) - mu * mu;
    const float rs = rsqrtf(var + 1e-5f);
    const float4 gv = ((const float4*)g1)[tid];
    const float4 bv = ((const float4*)be1)[tid];
    ushort4 o;
    o.x = f2bf((v.x - mu) * rs * gv.x + bv.x);
    o.y = f2bf((v.y - mu) * rs * gv.y + bv.y);
    o.z = f2bf((v.z - mu) * rs * gv.z + bv.z);
    o.w = f2bf((v.w - mu) * rs * gv.w + bv.w);
    ((ushort4*)yln)[(size_t)row * (CD / 4) + tid] = o;
    return;
  }

  // ---- transpose tile
  __shared__ float t[32][33];
  const float* __restrict__ in;
  u16* __restrict__ out;
  int K, N, n0, k0;
  if (g == 0){
    const int w = id >> 10, tile = id & 1023;
    in = p.s[w]; out = p.d[w]; K = 1024; N = 1024;
    n0 = (tile & 31) * 32; k0 = (tile >> 5) * 32;
  } else if (g == 1){
    in = p.s[4]; out = p.d[4]; K = 1024; N = 4096;
    n0 = (id & 127) * 32; k0 = (id >> 7) * 32;
  } else {
    in = p.s[5]; out = p.d[5]; K = 4096; N = 1024;
    n0 = (id & 31) * 32; k0 = (id >> 5) * 32;
  }
  const int c = tid & 31, r4 = tid >> 5;
  #pragma unroll
  for (int i = 0; i < 4; i++){
    int r = r4 + i * 8;
    t[r][c] = in[(size_t)(k0 + r) * N + n0 + c];
  }
  __syncthreads();
  #pragma unroll
  for (int i = 0; i < 4; i++){
    int r = r4 + i * 8;
    out[(size_t)(n0 + r) * K + k0 + c] = f2bf(t[c][r]);
  }
}

// ---------------- LayerNorm: fp32 row [1024] -> bf16 row, one block per row
// MODE 0: LN only.  MODE 2: also write aux = v + bias (fp32, may alias xin)
template<int MODE>
__global__ __launch_bounds__(256)
void ln_bf16(const float* __restrict__ xin, const float* __restrict__ g,
             const float* __restrict__ be, u16* __restrict__ outp,
             float4* __restrict__ aux, const float* __restrict__ bias)
{
  const int row = blockIdx.x, tid = threadIdx.x;
  const int lane = tid & 63, wave = tid >> 6;
  const float4 v = ((const float4*)(xin + (size_t)row * CD))[tid];
  float s  = v.x + v.y + v.z + v.w;
  float s2 = v.x*v.x + v.y*v.y + v.z*v.z + v.w*v.w;
  #pragma unroll
  for (int m = 1; m < 64; m <<= 1){ s += __shfl_xor(s, m); s2 += __shfl_xor(s2, m); }
  __shared__ float red[8];
  if (lane == 0){ red[wave] = s; red[4 + wave] = s2; }

  if (MODE == 2){
    const float4 b4 = ((const float4*)bias)[tid];
    float4 w = v;
    w.x += b4.x; w.y += b4.y; w.z += b4.z; w.w += b4.w;
    aux[(size_t)row * 256 + tid] = w;
  }

  __syncthreads();
  s  = red[0] + red[1] + red[2] + red[3];
  s2 = red[4] + red[5] + red[6] + red[7];
  const float mu = s * (1.0f / CD);
  const float var = s2 * (1.0f / CD) - mu * mu;
  const float rs = rsqrtf(var + 1e-5f);
  const float4 gv = ((const float4*)g)[tid];
  const float4 bv = ((const float4*)be)[tid];
  ushort4 o;
  o.x = f2bf((v.x - mu) * rs * gv.x + bv.x);
  o.y = f2bf((v.y - mu) * rs * gv.y + bv.y);
  o.z = f2bf((v.z - mu) * rs * gv.z + bv.z);
  o.w = f2bf((v.w - mu) * rs * gv.w + bv.w);
  ((ushort4*)outp)[(size_t)row * (CD / 4) + tid] = o;
}

// ---------------- GEMM 128x128, dbuf + vmcnt pipeline + XOR-swizzled LDS.
// EPI 0 (QKV): store bf16, Q pre-scaled 0.125, n0>=vsplit -> V^T.
// EPI 1: +bias, relu, store bf16.
template<int EPI>
__global__ __launch_bounds__(256)
void gemm_bt(const u16* __restrict__ A, const u16* __restrict__ Bt,
             void* __restrict__ Cout, const float* __restrict__ bias,
             int M, int N, int K,
             int ldc, int vsplit, u16* __restrict__ vtout)
{
  __shared__ __align__(16) u16 lA[2][128 * 64];   // 32 KB
  __shared__ __align__(16) u16 lB[2][128 * 64];   // 32 KB
  const int tid = threadIdx.x;
  const int wave = tid >> 6, lane = tid & 63;

  // XCD-banded tile decode (n-fastest)
  const int G = gridDim.x;
  const int flat = blockIdx.x;
  const int t = (flat & 7) * (G >> 3) + (flat >> 3);
  const int NN = N >> 7;
  const int n_i = t % NN;
  const int m_i = t / NN;

  const int m0 = m_i * 128, n0 = n_i * 128;
  const int wm = (wave >> 1) * 64, wn = (wave & 1) * 64;
  const int lq = lane >> 4, lr = lane & 15;
  const int l7 = lr & 7;
  const int sw0 = ((lq ^ l7) << 3);        // swizzled block offset, kk=0
  const int sw1 = (((4 + lq) ^ l7) << 3);  // kk=32

  f32x4 acc[4][4] = {};

  const u16* Ab = A + (size_t)m0 * K;
  const u16* Bb = Bt + (size_t)n0 * K;
  const int srow = lane >> 3;                    // 0..7 within a 1KB chunk
  const int scol = (((lane & 7) ^ srow)) * 8;    // swizzled staging column

  auto stage = [&](int buf, int k0){
    #pragma unroll
    for (int i = 0; i < 4; i++){
      const int c = i * 4 + wave;          // chunk 0..15 (1 KB each)
      const int row = c * 8 + srow;
      gload_lds16(Ab + (size_t)row * K + k0 + scol, &lA[buf][c * 512]);
      gload_lds16(Bb + (size_t)row * K + k0 + scol, &lB[buf][c * 512]);
    }
  };

  const int nit = K >> 6;
  stage(0, 0);
  for (int i = 0; i < nit; i++){
    const int cb = i & 1;
    if (i + 1 < nit){
      stage(cb ^ 1, (i + 1) * 64);
      asm volatile("s_waitcnt vmcnt(8)\n\ts_barrier" ::: "memory");
    } else {
      asm volatile("s_waitcnt vmcnt(0)\n\ts_barrier" ::: "memory");
    }
    #pragma unroll
    for (int kh = 0; kh < 2; kh++){
      const int sw = kh ? sw1 : sw0;
      short8 aF[4], bF[4];
      #pragma unroll
      for (int i2 = 0; i2 < 4; i2++) aF[i2] = *(const short8*)&lA[cb][(wm + i2 * 16 + lr) * 64 + sw];
      #pragma unroll
      for (int j = 0; j < 4; j++) bF[j] = *(const short8*)&lB[cb][(wn + j * 16 + lr) * 64 + sw];
      #pragma unroll
      for (int i2 = 0; i2 < 4; i2++)
        #pragma unroll
        for (int j = 0; j < 4; j++)
          acc[i2][j] = __builtin_amdgcn_mfma_f32_16x16x32_bf16(aF[i2], bF[j], acc[i2][j], 0, 0, 0);
    }
    asm volatile("s_barrier" ::: "memory");
  }

  if (EPI == 0 && n0 >= vsplit){
    // V block: store transposed into vt[(b*16+h)*64+d][s], s = 4 consecutive rows
    #pragma unroll
    for (int i = 0; i < 4; i++){
      const int row0 = m0 + wm + i * 16 + lq * 4;
      const int bb = row0 >> 11, s = row0 & 2047;
      #pragma unroll
      for (int j = 0; j < 4; j++){
        const int col = n0 - vsplit + wn + j * 16 + lr;  // 0..1023 = h*64+d
        ushort4 o;
        o.x = f2bf(acc[i][j][0]); o.y = f2bf(acc[i][j][1]);
        o.z = f2bf(acc[i][j][2]); o.w = f2bf(acc[i][j][3]);
        *(ushort4*)&vtout[((size_t)(bb * 1024 + col)) * CS + s] = o;
      }
    }
    return;
  }

  // Q pre-scale for attention (EPI 0 / QKV only): cols < 1024 are Q
  const float osc = (EPI == 0 && n0 < 1024) ? 0.125f : 1.0f;

  #pragma unroll
  for (int i = 0; i < 4; i++){
    const int row = m0 + wm + i * 16 + lq * 4;
    #pragma unroll
    for (int j = 0; j < 4; j++){
      const int col = n0 + wn + j * 16 + lr;
      #pragma unroll
      for (int r = 0; r < 4; r++){
        float v = acc[i][j][r];
        const size_t off = (size_t)(row + r) * ldc + col;
        if (EPI == 0){
          ((u16*)Cout)[off] = f2bf(v * osc);
        } else {
          v += bias[col]; v = v > 0.0f ? v : 0.0f;
          ((u16*)Cout)[off] = f2bf(v);
        }
      }
    }
  }
}

// ---------------- GEMM 64x128, dbuf + vmcnt pipeline + XOR-swizzled LDS:
// Cout[M,N] (f32) = resid[M,N] (f32) + A[M,K] (bf16) * Bt[N,K]^T
__global__ __launch_bounds__(256)
void gemm_bt64(const u16* __restrict__ A, const u16* __restrict__ Bt,
               const float* __restrict__ resid, float* __restrict__ Cout,
               int M, int N, int K)
{
  __shared__ __align__(16) u16 lA[2][64 * 64];    // 16 KB
  __shared__ __align__(16) u16 lB[2][128 * 64];   // 32 KB
  const int tid = threadIdx.x;
  const int wave = tid >> 6, lane = tid & 63;

  const int G = gridDim.x;
  const int flat = blockIdx.x;
  const int t = (flat & 7) * (G >> 3) + (flat >> 3);
  const int NN = N >> 7;
  const int n_i = t % NN;
  const int m_i = t / NN;
  const int m0 = m_i * 64, n0 = n_i * 128;
  const int lq = lane >> 4, lr = lane & 15;
  const int l7 = lr & 7;
  const int sw0 = ((lq ^ l7) << 3);
  const int sw1 = (((4 + lq) ^ l7) << 3);

  f32x4 acc[4][2] = {};

  const u16* Ab = A + (size_t)m0 * K;
  const u16* Bb = Bt + (size_t)n0 * K;
  const int srow = lane >> 3;
  const int scol = (((lane & 7) ^ srow)) * 8;

  auto stage = [&](int buf, int kt){
    const int k0 = kt * 64;
    #pragma unroll
    for (int i = 0; i < 6; i++){
      const int c = i * 4 + wave;          // 0..23: chunks 0-7 = A, 8-23 = B
      if (c < 8){
        gload_lds16(Ab + (size_t)(c * 8 + srow) * K + k0 + scol, &lA[buf][c * 512]);
      } else {
        const int cb2 = c - 8;
        gload_lds16(Bb + (size_t)(cb2 * 8 + srow) * K + k0 + scol, &lB[buf][cb2 * 512]);
      }
    }
  };

  const int nit = K >> 6;
  stage(0, 0);
  for (int i = 0; i < nit; i++){
    const int cb = i & 1;
    if (i + 1 < nit){
      stage(cb ^ 1, i + 1);
      asm volatile("s_waitcnt vmcnt(6)\n\ts_barrier" ::: "memory");
    } else {
      asm volatile("s_waitcnt vmcnt(0)\n\ts_barrier" ::: "memory");
    }
    #pragma unroll
    for (int kh = 0; kh < 2; kh++){
      const int sw = kh ? sw1 : sw0;
      short8 aF[4], bF[2];
      #pragma unroll
      for (int i2 = 0; i2 < 4; i2++) aF[i2] = *(const short8*)&lA[cb][(i2 * 16 + lr) * 64 + sw];
      #pragma unroll
      for (int j = 0; j < 2; j++) bF[j] = *(const short8*)&lB[cb][(wave * 32 + j * 16 + lr) * 64 + sw];
      #pragma unroll
      for (int i2 = 0; i2 < 4; i2++)
        #pragma unroll
        for (int j = 0; j < 2; j++)
          acc[i2][j] = __builtin_amdgcn_mfma_f32_16x16x32_bf16(aF[i2], bF[j], acc[i2][j], 0, 0, 0);
    }
    asm volatile("s_barrier" ::: "memory");
  }

  #pragma unroll
  for (int i = 0; i < 4; i++){
    const int row = m0 + i * 16 + lq * 4;
    #pragma unroll
    for (int j = 0; j < 2; j++){
      const int col = n0 + wave * 32 + j * 16 + lr;
      #pragma unroll
      for (int r = 0; r < 4; r++){
        const size_t off = (size_t)(row + r) * N + col;
        Cout[off] = resid[off] + acc[i][j][r];
      }
    }
  }
}

// ---------------- causal flash attention, dbuf + vmcnt pipeline + swizzled KV.
// Grid: x = bh (XCD L2 locality), y = pair. No running max; Q pre-scaled 0.125.
// qk: bf16 [B*S][2048] (Q | K), vt: bf16 [B*H*DH][S], out: bf16 [B*S][1024]
__global__ __launch_bounds__(256)
void attn_kernel(const u16* __restrict__ qk, const u16* __restrict__ vt,
                 u16* __restrict__ outp)
{
  __shared__ __align__(16) u16 lK[2][64 * 64];   // [key][d]  16 KB
  __shared__ __align__(16) u16 lVt[2][64 * 64];  // [d][key]  16 KB
  __shared__ __align__(16) u16 lP[4][16 * 72];   // per-wave P, padded  9 KB
  const int tid = threadIdx.x, wave = tid >> 6, lane = tid & 63;
  const int lq = lane >> 4, lr = lane & 15;
  const int l7 = lr & 7;
  const int sw0 = ((lq ^ l7) << 3);
  const int sw1 = (((4 + lq) ^ l7) << 3);
  const int bh = blockIdx.x, b = bh >> 4, h = bh & 15;
  const int RS = 2048;
  const int srow = lane >> 3;
  const int scol = (((lane & 7) ^ srow)) * 8;

  const size_t kbase = (size_t)(b * CS) * RS + 1024 + h * CDH;
  const size_t vbase = (size_t)(bh * CDH) * CS;
  u16* lPw = lP[wave];

  auto stageKV = [&](int buf, int kt){
    #pragma unroll
    for (int cc = 0; cc < 2; cc++){
      const int c = wave * 2 + cc;             // chunk 0..7, 8 rows each
      gload_lds16(qk + kbase + (size_t)(kt * 64 + c * 8 + srow) * RS + scol, &lK[buf][c * 512]);
      gload_lds16(vt + vbase + (size_t)(c * 8 + srow) * CS + kt * 64 + scol, &lVt[buf][c * 512]);
    }
  };

  #pragma unroll 1
  for (int part = 0; part < 2; part++){
    const int iq = part ? (NQB - 1 - blockIdx.y) : blockIdx.y;
    const int q0 = iq * 64;
    const int ktmax = iq + 1;

    // Q fragments (A-layout): m = lr, k = lq*8 + j (+32); already * 0.125
    const int qrow = b * CS + q0 + wave * 16 + lr;
    const u16* qp = qk + (size_t)qrow * RS + h * CDH;
    const short8 qf0 = *(const short8*)(qp + lq * 8);
    const short8 qf1 = *(const short8*)(qp + 32 + lq * 8);

    f32x4 o[4] = {};
    float lsum[4] = {0.0f, 0.0f, 0.0f, 0.0f};

    stageKV(0, 0);
    for (int kt = 0; kt < ktmax; ++kt){
      const int cb = kt & 1;
      if (kt + 1 < ktmax){
        stageKV(cb ^ 1, kt + 1);
        asm volatile("s_waitcnt vmcnt(4)\n\ts_barrier" ::: "memory");
      } else {
        asm volatile("s_waitcnt vmcnt(0)\n\ts_barrier" ::: "memory");
      }

      // S = Q K^T : 16 q-rows x 64 keys (pre-scaled)
      f32x4 s[4] = {};
      #pragma unroll
      for (int nb = 0; nb < 4; nb++){
        const short8 bk0 = *(const short8*)&lK[cb][(nb * 16 + lr) * 64 + sw0];
        const short8 bk1 = *(const short8*)&lK[cb][(nb * 16 + lr) * 64 + sw1];
        s[nb] = __builtin_amdgcn_mfma_f32_16x16x32_bf16(qf0, bk0, s[nb], 0, 0, 0);
        s[nb] = __builtin_amdgcn_mfma_f32_16x16x32_bf16(qf1, bk1, s[nb], 0, 0, 0);
      }

      const bool diag = (kt + 1) == ktmax;       // only diagonal tile needs mask
      const int qg = q0 + wave * 16 + lq * 4;
      #pragma unroll
      for (int r = 0; r < 4; r++){
        float e0 = __expf(s[0][r]);
        float e1 = __expf(s[1][r]);
        float e2 = __expf(s[2][r]);
        float e3 = __expf(s[3][r]);
        if (diag){
          const int q = qg + r, kb = kt * 64 + lr;
          e0 = (kb      <= q) ? e0 : 0.0f;
          e1 = (kb + 16 <= q) ? e1 : 0.0f;
          e2 = (kb + 32 <= q) ? e2 : 0.0f;
          e3 = (kb + 48 <= q) ? e3 : 0.0f;
        }
        lsum[r] += (e0 + e1) + (e2 + e3);
        const int prow = (lq * 4 + r) * 72;
        lPw[prow + lr]      = f2bf_pos(e0);
        lPw[prow + 16 + lr] = f2bf_pos(e1);
        lPw[prow + 32 + lr] = f2bf_pos(e2);
        lPw[prow + 48 + lr] = f2bf_pos(e3);
      }

      // P: C-layout -> A-layout via per-wave LDS
      asm volatile("s_waitcnt lgkmcnt(0)" ::: "memory");
      const short8 pf0 = *(const short8*)&lPw[lr * 72 + lq * 8];
      const short8 pf1 = *(const short8*)&lPw[lr * 72 + 32 + lq * 8];

      #pragma unroll
      for (int nb = 0; nb < 4; nb++){
        const short8 bv0 = *(const short8*)&lVt[cb][(nb * 16 + lr) * 64 + sw0];
        const short8 bv1 = *(const short8*)&lVt[cb][(nb * 16 + lr) * 64 + sw1];
        o[nb] = __builtin_amdgcn_mfma_f32_16x16x32_bf16(pf0, bv0, o[nb], 0, 0, 0);
        o[nb] = __builtin_amdgcn_mfma_f32_16x16x32_bf16(pf1, bv1, o[nb], 0, 0, 0);
      }
      // protect buffer cb from overwrite by kt+2's stage
      asm volatile("s_barrier" ::: "memory");
    }

    // one reduction tree per part: sum over the 16 key-lanes (lr)
    #pragma unroll
    for (int r = 0; r < 4; r++){
      float l = lsum[r];
      l += __shfl_xor(l, 1);
      l += __shfl_xor(l, 2);
      l += __shfl_xor(l, 4);
      l += __shfl_xor(l, 8);
      const float inv = __builtin_amdgcn_rcpf(l);
      const size_t row = (size_t)(b * CS + q0 + wave * 16 + lq * 4 + r);
      #pragma unroll
      for (int nb = 0; nb < 4; nb++)
        outp[row * CD + h * CDH + nb * 16 + lr] = f2bf(o[nb][r] * inv);
    }
  }
}

extern "C" void kernel_launch(void* const* d_in, const int* in_sizes, int n_in,
                              void* d_out, int out_size, void* d_ws, size_t ws_size,
                              hipStream_t stream)
{
  const float* x   = (const float*)d_in[0];
  const float* Wq  = (const float*)d_in[2];
  const float* Wk  = (const float*)d_in[3];
  const float* Wv  = (const float*)d_in[4];
  const float* Wo  = (const float*)d_in[5];
  const float* w1  = (const float*)d_in[6];
  const float* b1  = (const float*)d_in[7];
  const float* w2  = (const float*)d_in[8];
  const float* b2  = (const float*)d_in[9];
  const float* g1  = (const float*)d_in[10];
  const float* be1 = (const float*)d_in[11];
  const float* g2  = (const float*)d_in[12];
  const float* be2 = (const float*)d_in[13];
  float* out = (float*)d_out;

  char* ws = (char*)d_ws;
  const size_t MB = 1u << 20;
  u16* yln    = (u16*)(ws);              // [4096][1024] bf16 (also hn)       8 MB
  u16* qk     = (u16*)(ws + 8  * MB);    // [4096][2048] bf16 (Q|K)          16 MB
  u16* vt     = (u16*)(ws + 24 * MB);    // [B*H*64][2048] bf16 (V^T)         8 MB
  u16* attn   = (u16*)(ws + 32 * MB);    // [4096][1024] bf16                 8 MB
  u16* mid    = (u16*)(ws + 40 * MB);    // [4096][4096] bf16                32 MB
  u16* Wqkv_t = (u16*)(ws + 72 * MB);    // [3072][1024] bf16                 6 MB
  u16* Wo_t   = (u16*)(ws + 78 * MB);    // [1024][1024] bf16                 2 MB
  u16* w1_t   = (u16*)(ws + 80 * MB);    // [4096][1024] bf16                 8 MB
  u16* w2_t   = (u16*)(ws + 88 * MB);    // [1024][4096] bf16                 8 MB

  const int M = CB * CS;  // 4096
  const int BIG = 1 << 30;

  // prep: all 6 transposes + LN1 fused in one launch
  TPAll pa;
  pa.s[0] = Wq; pa.s[1] = Wk; pa.s[2] = Wv; pa.s[3] = Wo; pa.s[4] = w1; pa.s[5] = w2;
  pa.d[0] = Wqkv_t;
  pa.d[1] = Wqkv_t + (size_t)CD * CD;
  pa.d[2] = Wqkv_t + (size_t)2 * CD * CD;
  pa.d[3] = Wo_t;
  pa.d[4] = w1_t;
  pa.d[5] = w2_t;
  prep_all<<<4 * 4096, 256, 0, stream>>>(pa, x, g1, be1, yln);

  // QKV: Q,K -> qk (ldc=2048, Q pre-scaled 0.125); V -> vt (transposed)
  gemm_bt<0><<<24 * 32, 256, 0, stream>>>(yln, Wqkv_t, qk, nullptr, M, 3 * CD, CD, 2048, 2048, vt);
  // attention (grid: x=bh for XCD L2 locality, y=pair)
  attn_kernel<<<dim3(CB * CH, NQB / 2), 256, 0, stream>>>(qk, vt, attn);
  // h = x + attn @ Wo   (64x128 tiles, dbuf pipeline, resid = x)
  gemm_bt64<<<64 * 8, 256, 0, stream>>>(attn, Wo_t, x, out, M, CD, CD);
  // LN2: h -> hn (bf16); also out = h + b2 in-place (residual+bias for FFN2)
  ln_bf16<2><<<M, 256, 0, stream>>>(out, g2, be2, yln, (float4*)out, b2);
  // mid = relu(hn @ w1 + b1)  (128x128 dbuf pipeline)
  gemm_bt<1><<<32 * 32, 256, 0, stream>>>(yln, w1_t, mid, b1, M, CDFF, CD, CDFF, BIG, nullptr);
  // out = (h + b2) + mid @ w2   (64x128 tiles, dbuf pipeline, 64 k-iters)
  gemm_bt64<<<64 * 8, 256, 0, stream>>>(mid, w2_t, out, out, M, CD, CDFF);
}